// Round 9
// baseline (826.531 us; speedup 1.0000x reference)
//
#include <hip/hip_runtime.h>
#include <math.h>

#define NN   100000
#define HH   128
#define INF_ 35
#define GG   1000
#define LBM  64
#define BKG  32

static __device__ __forceinline__ float silu_f(float x){ return x / (1.f + __expf(-x)); }
static __device__ __forceinline__ unsigned bf16rne(float x){
    unsigned u = __float_as_uint(x);
    return (u + 0x7FFFu + ((u>>16)&1u)) >> 16;
}
#define BN_INV 0.9999950000374997f  /* 1/sqrt(1+1e-5) */

// ---------------- stacked CSR build (both graphs, dst' = dst + n*branch) ----------------
__global__ void k_count(const int* __restrict__ ei1, const int* __restrict__ ei2,
                        int E1, int E2, int n, int* __restrict__ deg){
    int e = blockIdx.x*256 + threadIdx.x;
    int ET = E1 + E2;
    if (e >= ET) return;
    int c;
    if (e < E1) c = ei1[E1 + e];
    else        c = n + ei2[E2 + (e - E1)];
    atomicAdd(&deg[c], 1);
}

__global__ void k_scan1(const int* __restrict__ deg, int n2, int* __restrict__ off, int* __restrict__ bsum){
    __shared__ int s[256];
    int tid = threadIdx.x; int i = blockIdx.x*256 + tid;
    int v = (i<n2)? deg[i] : 0;
    s[tid] = v; __syncthreads();
    for (int ofs=1; ofs<256; ofs<<=1){
        int t = (tid>=ofs)? s[tid-ofs] : 0;
        __syncthreads(); s[tid] += t; __syncthreads();
    }
    if (i<n2) off[i] = s[tid] - v;
    if (tid==255) bsum[blockIdx.x] = s[255];
}

__global__ void k_scan2(int* __restrict__ bsum, int nb){
    __shared__ int s[1024];
    int tid = threadIdx.x;
    int v = (tid<nb)? bsum[tid] : 0;
    s[tid] = v; __syncthreads();
    for (int ofs=1; ofs<1024; ofs<<=1){
        int t = (tid>=ofs)? s[tid-ofs] : 0;
        __syncthreads(); s[tid] += t; __syncthreads();
    }
    if (tid<nb) bsum[tid] = s[tid] - v;
}

__global__ void k_scan3(int* __restrict__ off, const int* __restrict__ bsum, int n2, int ET){
    int i = blockIdx.x*256 + threadIdx.x;
    if (i<n2) off[i] += bsum[i>>8];
    if (i==0) off[n2] = ET;
}

// fill stacked CSR records: {rb[0..8], src, d, pad} = 48B
__global__ void k_fill(const int* __restrict__ ei1, const int* __restrict__ ei2,
                       int E1, int E2, int n, const float* __restrict__ pos,
                       const int* __restrict__ off, int* __restrict__ cur,
                       float4* __restrict__ rec){
    int e = blockIdx.x*256 + threadIdx.x;
    int ET = E1 + E2;
    if (e >= ET) return;
    int r, creal, cslot;
    if (e < E1){ r = ei1[e];        creal = ei1[E1 + e];        cslot = creal; }
    else       { int ee = e - E1; r = ei2[ee]; creal = ei2[E2 + ee]; cslot = n + creal; }
    int slot = atomicAdd(&cur[cslot], 1);
    int p = off[cslot] + slot;
    float dx = pos[r*3+0]-pos[creal*3+0];
    float dy = pos[r*3+1]-pos[creal*3+1];
    float dz = pos[r*3+2]-pos[creal*3+2];
    float d  = sqrtf(dx*dx + dy*dy + dz*dz);
    float rb[9];
    #pragma unroll
    for (int k=0;k<9;k++){
        float t = (d - 0.75f*(float)k) * 1.5f;
        rb[k] = __expf(-t*t);
    }
    rec[(size_t)p*3+0] = make_float4(rb[0],rb[1],rb[2],rb[3]);
    rec[(size_t)p*3+1] = make_float4(rb[4],rb[5],rb[6],rb[7]);
    rec[(size_t)p*3+2] = make_float4(rb[8], __int_as_float(r), d, 0.f);
}

// ---------------- input: h = silu(x @ W_in + b), also bf16 mirror ----------------
#define NT_IN (NN/16)
__global__ __launch_bounds__(256) void k_input(const float* __restrict__ x, const float* __restrict__ W,
                        const float* __restrict__ b, float* __restrict__ h,
                        unsigned short* __restrict__ hb){
    __shared__ __align__(16) float xs[16][36];
    int tx = threadIdx.x;
    int c = tx & 127, g = tx >> 7;
    float4 wv[9];
    {
        float* wf = (float*)wv;
        #pragma unroll
        for (int k=0;k<INF_;k++) wf[k] = W[k*HH + c];
        wf[35] = 0.f;
    }
    float bc = b[c];
    for (int tile = blockIdx.x; tile < NT_IN; tile += gridDim.x){
        int r0 = tile*16;
        for (int i = tx; i < 16*INF_; i += 256){
            int rr = i/INF_, kk = i - rr*INF_;
            xs[rr][kk] = x[(size_t)(r0+rr)*INF_ + kk];
        }
        if (tx < 16) xs[tx][35] = 0.f;
        __syncthreads();
        float acc[8];
        #pragma unroll
        for (int j=0;j<8;j++) acc[j] = bc;
        #pragma unroll
        for (int kk=0;kk<9;kk++){
            float4 w4 = wv[kk];
            #pragma unroll
            for (int j=0;j<8;j++){
                float4 xv = *(const float4*)(&xs[g*8+j][kk*4]);
                acc[j] += xv.x*w4.x + xv.y*w4.y + xv.z*w4.z + xv.w*w4.w;
            }
        }
        #pragma unroll
        for (int j=0;j<8;j++){
            int gr = r0 + g*8 + j;
            float v = silu_f(acc[j]);
            h[(size_t)gr*HH + c] = v;
            hb[(size_t)gr*HH + c] = (unsigned short)bf16rne(v);
        }
        __syncthreads();
    }
}

// ---------------- merged dual-branch gather (bf16 neighbor reads) ----------------
#define QPAIR(A0,A1,A2X,Q0,Q1)              \
    float Q0 = cb.x, Q1 = cb.y;             \
    Q0 += A0.x*w0[0]; Q1 += A0.x*w1[0];     \
    Q0 += A0.y*w0[1]; Q1 += A0.y*w1[1];     \
    Q0 += A0.z*w0[2]; Q1 += A0.z*w1[2];     \
    Q0 += A0.w*w0[3]; Q1 += A0.w*w1[3];     \
    Q0 += A1.x*w0[4]; Q1 += A1.x*w1[4];     \
    Q0 += A1.y*w0[5]; Q1 += A1.y*w1[5];     \
    Q0 += A1.z*w0[6]; Q1 += A1.z*w1[6];     \
    Q0 += A1.w*w0[7]; Q1 += A1.w*w1[7];     \
    Q0 += A2X*w0[8];  Q1 += A2X*w1[8];

__global__ __launch_bounds__(256) void k_gather(const float* __restrict__ h,
        const unsigned short* __restrict__ hb,
        const int* __restrict__ off, const float4* __restrict__ rec,
        const float* __restrict__ cWl, const float* __restrict__ cBl,
        float* __restrict__ agg1, float* __restrict__ agg2, int n, int nblk1){
    int b = blockIdx.x;
    int br = (b >= nblk1) ? 1 : 0;
    int node = (br ? b - nblk1 : b)*4 + (threadIdx.x>>6);
    if (node >= n) return;
    int c = (threadIdx.x & 63)*2;
    const float* cW = cWl + br*(9*HH);
    const float* cB = cBl + br*HH;
    float* aggp = br ? agg2 : agg1;

    float w0[9], w1[9];
    #pragma unroll
    for (int k=0;k<9;k++){
        float2 t = *(const float2*)(cW + k*HH + c);
        w0[k]=t.x; w1[k]=t.y;
    }
    float2 cb = *(const float2*)(cB + c);
    float2 acc = *(const float2*)(h + (size_t)node*HH + c);

    int slot = node + br*n;
    int lo = off[slot], hi = off[slot+1];
    lo = __builtin_amdgcn_readfirstlane(lo);
    hi = __builtin_amdgcn_readfirstlane(hi);

    const float4* rp = rec + (size_t)lo*3;
    int p = lo;
    for (; p+2<=hi; p+=2, rp+=6){
        float4 e0a = rp[0], e0b = rp[1], e0c = rp[2];
        float4 e1a = rp[3], e1b = rp[4], e1c = rp[5];
        int s0 = __float_as_int(e0c.y);
        int s1 = __float_as_int(e1c.y);
        unsigned u0 = *(const unsigned*)(hb + (size_t)s0*HH + c);
        unsigned u1 = *(const unsigned*)(hb + (size_t)s1*HH + c);
        float hv0x = __uint_as_float(u0<<16), hv0y = __uint_as_float(u0 & 0xFFFF0000u);
        float hv1x = __uint_as_float(u1<<16), hv1y = __uint_as_float(u1 & 0xFFFF0000u);
        QPAIR(e0a, e0b, e0c.x, q00, q01)
        QPAIR(e1a, e1b, e1c.x, q10, q11)
        acc.x += hv0x * silu_f(q00);
        acc.y += hv0y * silu_f(q01);
        acc.x += hv1x * silu_f(q10);
        acc.y += hv1y * silu_f(q11);
    }
    if (p < hi){
        float4 e0a = rp[0], e0b = rp[1], e0c = rp[2];
        int s0 = __float_as_int(e0c.y);
        unsigned u0 = *(const unsigned*)(hb + (size_t)s0*HH + c);
        float hv0x = __uint_as_float(u0<<16), hv0y = __uint_as_float(u0 & 0xFFFF0000u);
        QPAIR(e0a, e0b, e0c.x, q00, q01)
        acc.x += hv0x * silu_f(q00);
        acc.y += hv0y * silu_f(q01);
    }
    *(float2*)(aggp + (size_t)node*HH + c) = acc;
}

// ---------------- dual-branch node GEMM: 8.7KB LDS (32-k A tile), occupancy-first ----------------
#define GK(K, BV, ACC) {                                                      \
    float4 a0 = *(const float4*)(&As[K][r0]);                                 \
    float4 a1 = *(const float4*)(&As[K][r0+4]);                               \
    ACC[0][0]+=a0.x*BV.x; ACC[0][1]+=a0.x*BV.y; ACC[0][2]+=a0.x*BV.z; ACC[0][3]+=a0.x*BV.w; \
    ACC[1][0]+=a0.y*BV.x; ACC[1][1]+=a0.y*BV.y; ACC[1][2]+=a0.y*BV.z; ACC[1][3]+=a0.y*BV.w; \
    ACC[2][0]+=a0.z*BV.x; ACC[2][1]+=a0.z*BV.y; ACC[2][2]+=a0.z*BV.z; ACC[2][3]+=a0.z*BV.w; \
    ACC[3][0]+=a0.w*BV.x; ACC[3][1]+=a0.w*BV.y; ACC[3][2]+=a0.w*BV.z; ACC[3][3]+=a0.w*BV.w; \
    ACC[4][0]+=a1.x*BV.x; ACC[4][1]+=a1.x*BV.y; ACC[4][2]+=a1.x*BV.z; ACC[4][3]+=a1.x*BV.w; \
    ACC[5][0]+=a1.y*BV.x; ACC[5][1]+=a1.y*BV.y; ACC[5][2]+=a1.y*BV.z; ACC[5][3]+=a1.y*BV.w; \
    ACC[6][0]+=a1.z*BV.x; ACC[6][1]+=a1.z*BV.y; ACC[6][2]+=a1.z*BV.z; ACC[6][3]+=a1.z*BV.w; \
    ACC[7][0]+=a1.w*BV.x; ACC[7][1]+=a1.w*BV.y; ACC[7][2]+=a1.w*BV.z; ACC[7][3]+=a1.w*BV.w; }

// stage one 64-row x 32-k tile: 512 float4, 2 per thread; row = q&63 -> 2-way-free LDS writes
#define STAGE_TILE(AP, KT) {                                                  \
    _Pragma("unroll")                                                         \
    for (int rep=0; rep<2; rep++){                                            \
        int q = rep*256 + tx;                                                 \
        int row = q & 63;                                                     \
        int kk  = (q>>6)*4;                                                   \
        float4 v = make_float4(0.f,0.f,0.f,0.f);                              \
        int gr = rb + row;                                                    \
        if (gr < n) v = *(const float4*)((AP) + (size_t)gr*HH + (KT) + kk);   \
        As[kk+0][row]=v.x; As[kk+1][row]=v.y;                                 \
        As[kk+2][row]=v.z; As[kk+3][row]=v.w;                                 \
    } }

#define GEMM_TILE(BP, KT, ACC) {                                              \
    const float* Bc = (BP) + c0 + (size_t)(KT)*HH;                            \
    float4 bva0 = *(const float4*)(Bc + 0*HH);                                \
    float4 bva1 = *(const float4*)(Bc + 1*HH);                                \
    float4 bva2 = *(const float4*)(Bc + 2*HH);                                \
    float4 bva3 = *(const float4*)(Bc + 3*HH);                                \
    _Pragma("unroll")                                                         \
    for (int k=0;k<BKG;k+=8){                                                 \
        float4 bvb0 = *(const float4*)(Bc + (k+4)*HH);                        \
        float4 bvb1 = *(const float4*)(Bc + (k+5)*HH);                        \
        float4 bvb2 = *(const float4*)(Bc + (k+6)*HH);                        \
        float4 bvb3 = *(const float4*)(Bc + (k+7)*HH);                        \
        GK(k+0, bva0, ACC) GK(k+1, bva1, ACC)                                 \
        GK(k+2, bva2, ACC) GK(k+3, bva3, ACC)                                 \
        if (k+8 < BKG){                                                       \
            bva0 = *(const float4*)(Bc + (k+8)*HH);                           \
            bva1 = *(const float4*)(Bc + (k+9)*HH);                           \
            bva2 = *(const float4*)(Bc + (k+10)*HH);                          \
            bva3 = *(const float4*)(Bc + (k+11)*HH);                          \
        }                                                                     \
        GK(k+4, bvb0, ACC) GK(k+5, bvb1, ACC)                                 \
        GK(k+6, bvb2, ACC) GK(k+7, bvb3, ACC)                                 \
    } }

__global__ __launch_bounds__(256) void k_gemm2(
        const float* __restrict__ A1, const float* __restrict__ A2,
        const float* __restrict__ B1, const float* __restrict__ B2,
        const float* __restrict__ b1, const float* __restrict__ b2,
        const float* __restrict__ g1, const float* __restrict__ g2,
        const float* __restrict__ e1, const float* __restrict__ e2,
        float* __restrict__ C, unsigned short* __restrict__ Cb, int n){
    __shared__ __align__(16) float As[BKG][LBM+4];   // 32 x 68 = 8.7 KB
    int tx = threadIdx.x;
    int rb = blockIdx.x*LBM;
    int c0 = (tx&31)*4, r0 = (tx>>5)*8;
    float acc1[8][4], acc2[8][4];
    #pragma unroll
    for (int j=0;j<8;j++){
        #pragma unroll
        for (int q=0;q<4;q++){ acc1[j][q]=0.f; acc2[j][q]=0.f; }
    }

    for (int kt=0; kt<HH; kt+=BKG){
        STAGE_TILE(A1, kt)
        __syncthreads();
        GEMM_TILE(B1, kt, acc1)
        __syncthreads();
    }
    for (int kt=0; kt<HH; kt+=BKG){
        STAGE_TILE(A2, kt)
        __syncthreads();
        GEMM_TILE(B2, kt, acc2)
        __syncthreads();
    }

    float4 bi1 = *(const float4*)(b1 + c0);
    float4 ga1 = *(const float4*)(g1 + c0);
    float4 bt1 = *(const float4*)(e1 + c0);
    float4 bi2 = *(const float4*)(b2 + c0);
    float4 ga2 = *(const float4*)(g2 + c0);
    float4 bt2 = *(const float4*)(e2 + c0);
    #pragma unroll
    for (int j=0;j<8;j++){
        int gr = rb + r0 + j;
        if (gr < n){
            float x0,x1,x2,x3,y0,y1,y2,y3;
            x0 = acc1[j][0]+bi1.x; x1 = acc1[j][1]+bi1.y; x2 = acc1[j][2]+bi1.z; x3 = acc1[j][3]+bi1.w;
            x0 = (x0>=0.f)? x0 : 0.01f*x0;  x1 = (x1>=0.f)? x1 : 0.01f*x1;
            x2 = (x2>=0.f)? x2 : 0.01f*x2;  x3 = (x3>=0.f)? x3 : 0.01f*x3;
            y0 = acc2[j][0]+bi2.x; y1 = acc2[j][1]+bi2.y; y2 = acc2[j][2]+bi2.z; y3 = acc2[j][3]+bi2.w;
            y0 = (y0>=0.f)? y0 : 0.01f*y0;  y1 = (y1>=0.f)? y1 : 0.01f*y1;
            y2 = (y2>=0.f)? y2 : 0.01f*y2;  y3 = (y3>=0.f)? y3 : 0.01f*y3;
            float4 o;
            o.x = (ga1.x*x0 + ga2.x*y0)*BN_INV + bt1.x + bt2.x;
            o.y = (ga1.y*x1 + ga2.y*y1)*BN_INV + bt1.y + bt2.y;
            o.z = (ga1.z*x2 + ga2.z*y2)*BN_INV + bt1.z + bt2.z;
            o.w = (ga1.w*x3 + ga2.w*y3)*BN_INV + bt1.w + bt2.w;
            *(float4*)(C + (size_t)gr*HH + c0) = o;
            uint2 pb;
            pb.x = bf16rne(o.x) | (bf16rne(o.y)<<16);
            pb.y = bf16rne(o.z) | (bf16rne(o.w)<<16);
            *(uint2*)(Cb + (size_t)gr*HH + c0) = pb;
        }
    }
}

// ---------------- fused pool + FC x3 + head ----------------
static __device__ __forceinline__ int lower_bound_i(const int* __restrict__ a, int n, int key){
    int lo=0, hi=n;
    while (lo<hi){ int m=(lo+hi)>>1; if (a[m]<key) lo=m+1; else hi=m; }
    return lo;
}
__global__ void k_poolfc(const float* __restrict__ h, const int* __restrict__ batch,
                     const float* __restrict__ fcW, const float* __restrict__ fcB,
                     const float* __restrict__ fbg, const float* __restrict__ fbb,
                     const float* __restrict__ outW, const float* __restrict__ outB,
                     float* __restrict__ out, int n){
    __shared__ float row[HH];
    __shared__ float red[2];
    int g = blockIdx.x, c = threadIdx.x;
    int lo = lower_bound_i(batch, n, g);
    int hi = lower_bound_i(batch, n, g+1);
    float v = 0.f;
    for (int r=lo; r<hi; r++) v += h[(size_t)r*HH + c];
    for (int l=0;l<3;l++){
        row[c] = v; __syncthreads();
        float acc = fcB[l*HH + c];
        const float* W = fcW + (size_t)l*HH*HH;
        #pragma unroll 8
        for (int k=0;k<HH;k++) acc += row[k]*W[k*HH + c];
        acc = (acc>=0.f)? acc : 0.01f*acc;
        v = fbg[l*HH+c]*acc*BN_INV + fbb[l*HH+c];
        __syncthreads();
    }
    float t = v * outW[c];
    #pragma unroll
    for (int o=32;o>0;o>>=1) t += __shfl_down(t, o, 64);
    if ((c&63)==0) red[c>>6] = t;
    __syncthreads();
    if (c==0) out[g] = red[0] + red[1] + outB[0];
}

extern "C" void kernel_launch(void* const* d_in, const int* in_sizes, int n_in,
                              void* d_out, int out_size, void* d_ws, size_t ws_size,
                              hipStream_t stream){
    const float* x      = (const float*)d_in[0];
    const float* pos    = (const float*)d_in[1];
    const float* W_in   = (const float*)d_in[2];
    const float* b_in   = (const float*)d_in[3];
    const float* coordW = (const float*)d_in[4];
    const float* coordB = (const float*)d_in[5];
    const float* nodeW  = (const float*)d_in[6];
    const float* nodeB  = (const float*)d_in[7];
    const float* bnG    = (const float*)d_in[8];
    const float* bnB    = (const float*)d_in[9];
    const float* fcW    = (const float*)d_in[10];
    const float* fcB    = (const float*)d_in[11];
    const float* fcBnG  = (const float*)d_in[12];
    const float* fcBnB  = (const float*)d_in[13];
    const float* outW   = (const float*)d_in[14];
    const float* outB   = (const float*)d_in[15];
    const int* ei1      = (const int*)d_in[16];
    const int* ei2      = (const int*)d_in[17];
    const int* batch    = (const int*)d_in[18];
    const int E1 = in_sizes[16]/2, E2 = in_sizes[17]/2;
    const int n = NN;
    const int n2 = 2*n;
    const int ET = E1 + E2;

    char* w = (char*)d_ws;
    size_t o = 0;
    auto alloc = [&](size_t bytes)->void*{
        void* r = w + o;
        o += (bytes + 255) & ~(size_t)255;
        return r;
    };
    float*  h    = (float*)alloc((size_t)n*HH*4);
    float*  h2   = (float*)alloc((size_t)n*HH*4);
    float*  agg  = (float*)alloc((size_t)n*HH*4);
    unsigned short* hb  = (unsigned short*)alloc((size_t)n*HH*2);
    unsigned short* hb2 = (unsigned short*)alloc((size_t)n*HH*2);
    int*    off  = (int*)alloc((size_t)(n2+1)*4);
    int*    cnt  = (int*)alloc((size_t)n2*4);   // cnt and cur adjacent -> one memset
    int*    cur  = (int*)alloc((size_t)n2*4);
    float4* rec  = (float4*)alloc((size_t)ET*48);
    int*    bsum = (int*)alloc(1024*4);
    (void)ws_size; (void)n_in; (void)out_size;

    int nb2 = (n2+255)/256;

    hipMemsetAsync(cnt, 0, (size_t)2*n2*4, stream);
    k_count<<<(ET+255)/256,256,0,stream>>>(ei1, ei2, E1, E2, n, cnt);
    k_scan1<<<nb2,256,0,stream>>>(cnt, n2, off, bsum);
    k_scan2<<<1,1024,0,stream>>>(bsum, nb2);
    k_scan3<<<nb2,256,0,stream>>>(off, bsum, n2, ET);
    k_fill<<<(ET+255)/256,256,0,stream>>>(ei1, ei2, E1, E2, n, pos, off, cur, rec);

    k_input<<<2048,256,0,stream>>>(x, W_in, b_in, h, hb);

    int nb4 = (n+3)/4;
    float* hcur = h;  unsigned short* hbcur = hb;
    float* hoth = h2; unsigned short* hboth = hb2;
    for (int l=0; l<3; l++){
        int li0 = l*2, li1 = l*2+1;
        // gather both branches: branch0 -> agg, branch1 -> hoth (overwritten in place by gemm2)
        k_gather<<<2*nb4,256,0,stream>>>(hcur, hbcur, off, rec,
            coordW + (size_t)li0*9*HH, coordB + (size_t)li0*HH, agg, hoth, n, nb4);
        k_gemm2<<<(n+LBM-1)/LBM,256,0,stream>>>(agg, hoth,
            nodeW + (size_t)li0*HH*HH, nodeW + (size_t)li1*HH*HH,
            nodeB + (size_t)li0*HH,  nodeB + (size_t)li1*HH,
            bnG   + (size_t)li0*HH,  bnG   + (size_t)li1*HH,
            bnB   + (size_t)li0*HH,  bnB   + (size_t)li1*HH,
            hoth, hboth, n);
        float* t = hcur; hcur = hoth; hoth = t;
        unsigned short* tb = hbcur; hbcur = hboth; hboth = tb;
    }

    k_poolfc<<<GG,128,0,stream>>>(hcur, batch, fcW, fcB, fcBnG, fcBnB, outW, outB, (float*)d_out, n);
}

// Round 10
// 734.084 us; speedup vs baseline: 1.1259x; 1.1259x over previous
//
#include <hip/hip_runtime.h>
#include <math.h>

#define NN   100000
#define HH   128
#define INF_ 35
#define GG   1000
#define LBM  64

typedef __attribute__((ext_vector_type(8))) short short8;
typedef __attribute__((ext_vector_type(4))) float f32x4;

static __device__ __forceinline__ float silu_f(float x){ return x / (1.f + __expf(-x)); }
static __device__ __forceinline__ unsigned bf16rne(float x){
    unsigned u = __float_as_uint(x);
    return (u + 0x7FFFu + ((u>>16)&1u)) >> 16;
}
#define BN_INV 0.9999950000374997f  /* 1/sqrt(1+1e-5) */

// ---------------- stacked CSR build (both graphs, dst' = dst + n*branch) ----------------
__global__ void k_count(const int* __restrict__ ei1, const int* __restrict__ ei2,
                        int E1, int E2, int n, int* __restrict__ deg){
    int e = blockIdx.x*256 + threadIdx.x;
    int ET = E1 + E2;
    if (e >= ET) return;
    int c;
    if (e < E1) c = ei1[E1 + e];
    else        c = n + ei2[E2 + (e - E1)];
    atomicAdd(&deg[c], 1);
}

__global__ void k_scan1(const int* __restrict__ deg, int n2, int* __restrict__ off, int* __restrict__ bsum){
    __shared__ int s[256];
    int tid = threadIdx.x; int i = blockIdx.x*256 + tid;
    int v = (i<n2)? deg[i] : 0;
    s[tid] = v; __syncthreads();
    for (int ofs=1; ofs<256; ofs<<=1){
        int t = (tid>=ofs)? s[tid-ofs] : 0;
        __syncthreads(); s[tid] += t; __syncthreads();
    }
    if (i<n2) off[i] = s[tid] - v;
    if (tid==255) bsum[blockIdx.x] = s[255];
}

__global__ void k_scan2(int* __restrict__ bsum, int nb){
    __shared__ int s[1024];
    int tid = threadIdx.x;
    int v = (tid<nb)? bsum[tid] : 0;
    s[tid] = v; __syncthreads();
    for (int ofs=1; ofs<1024; ofs<<=1){
        int t = (tid>=ofs)? s[tid-ofs] : 0;
        __syncthreads(); s[tid] += t; __syncthreads();
    }
    if (tid<nb) bsum[tid] = s[tid] - v;
}

__global__ void k_scan3(int* __restrict__ off, const int* __restrict__ bsum, int n2, int ET){
    int i = blockIdx.x*256 + threadIdx.x;
    if (i<n2) off[i] += bsum[i>>8];
    if (i==0) off[n2] = ET;
}

// fill stacked CSR records: {rb[0..8], src, d, pad} = 48B
__global__ void k_fill(const int* __restrict__ ei1, const int* __restrict__ ei2,
                       int E1, int E2, int n, const float* __restrict__ pos,
                       const int* __restrict__ off, int* __restrict__ cur,
                       float4* __restrict__ rec){
    int e = blockIdx.x*256 + threadIdx.x;
    int ET = E1 + E2;
    if (e >= ET) return;
    int r, creal, cslot;
    if (e < E1){ r = ei1[e];        creal = ei1[E1 + e];        cslot = creal; }
    else       { int ee = e - E1; r = ei2[ee]; creal = ei2[E2 + ee]; cslot = n + creal; }
    int slot = atomicAdd(&cur[cslot], 1);
    int p = off[cslot] + slot;
    float dx = pos[r*3+0]-pos[creal*3+0];
    float dy = pos[r*3+1]-pos[creal*3+1];
    float dz = pos[r*3+2]-pos[creal*3+2];
    float d  = sqrtf(dx*dx + dy*dy + dz*dz);
    float rb[9];
    #pragma unroll
    for (int k=0;k<9;k++){
        float t = (d - 0.75f*(float)k) * 1.5f;
        rb[k] = __expf(-t*t);
    }
    rec[(size_t)p*3+0] = make_float4(rb[0],rb[1],rb[2],rb[3]);
    rec[(size_t)p*3+1] = make_float4(rb[4],rb[5],rb[6],rb[7]);
    rec[(size_t)p*3+2] = make_float4(rb[8], __int_as_float(r), d, 0.f);
}

// ---------------- pack nodeW (6 matrices) into MFMA B-fragment layout, bf16 ----------------
// Bpk[li][s][ct][l][j] = bf16(nodeW[li][s*32+(l>>4)*8+j][ct*16+(l&15)])
__global__ void k_pack(const float* __restrict__ nodeW, unsigned short* __restrict__ Bpk){
    int idx = blockIdx.x*256 + threadIdx.x;          // 6*2048 = 12288
    if (idx >= 6*2048) return;
    int li = idx >> 11;
    int r  = idx & 2047;
    int s  = r >> 9;
    int r2 = r & 511;
    int ct = r2 >> 6;
    int l  = r2 & 63;
    const float* src = nodeW + (size_t)li*16384 + (size_t)(s*32 + (l>>4)*8)*HH + ct*16 + (l&15);
    unsigned short o[8];
    #pragma unroll
    for (int j=0;j<8;j++) o[j] = (unsigned short)bf16rne(src[(size_t)j*HH]);
    uint4 v;
    v.x = o[0] | ((unsigned)o[1]<<16);
    v.y = o[2] | ((unsigned)o[3]<<16);
    v.z = o[4] | ((unsigned)o[5]<<16);
    v.w = o[6] | ((unsigned)o[7]<<16);
    *(uint4*)(Bpk + (size_t)idx*8) = v;
}

// ---------------- input: h = silu(x @ W_in + b), fp32 (optional) + bf16 mirror ----------------
#define NT_IN (NN/16)
__global__ __launch_bounds__(256) void k_input(const float* __restrict__ x, const float* __restrict__ W,
                        const float* __restrict__ b, float* __restrict__ h,
                        unsigned short* __restrict__ hb){
    __shared__ __align__(16) float xs[16][36];
    int tx = threadIdx.x;
    int c = tx & 127, g = tx >> 7;
    float4 wv[9];
    {
        float* wf = (float*)wv;
        #pragma unroll
        for (int k=0;k<INF_;k++) wf[k] = W[k*HH + c];
        wf[35] = 0.f;
    }
    float bc = b[c];
    for (int tile = blockIdx.x; tile < NT_IN; tile += gridDim.x){
        int r0 = tile*16;
        for (int i = tx; i < 16*INF_; i += 256){
            int rr = i/INF_, kk = i - rr*INF_;
            xs[rr][kk] = x[(size_t)(r0+rr)*INF_ + kk];
        }
        if (tx < 16) xs[tx][35] = 0.f;
        __syncthreads();
        float acc[8];
        #pragma unroll
        for (int j=0;j<8;j++) acc[j] = bc;
        #pragma unroll
        for (int kk=0;kk<9;kk++){
            float4 w4 = wv[kk];
            #pragma unroll
            for (int j=0;j<8;j++){
                float4 xv = *(const float4*)(&xs[g*8+j][kk*4]);
                acc[j] += xv.x*w4.x + xv.y*w4.y + xv.z*w4.z + xv.w*w4.w;
            }
        }
        #pragma unroll
        for (int j=0;j<8;j++){
            int gr = r0 + g*8 + j;
            float v = silu_f(acc[j]);
            if (h) h[(size_t)gr*HH + c] = v;
            hb[(size_t)gr*HH + c] = (unsigned short)bf16rne(v);
        }
        __syncthreads();
    }
}

// ---------------- merged dual-branch gather (bf16 neighbor reads, bf16 agg out) ----------------
#define QPAIR(A0,A1,A2X,Q0,Q1)              \
    float Q0 = cb.x, Q1 = cb.y;             \
    Q0 += A0.x*w0[0]; Q1 += A0.x*w1[0];     \
    Q0 += A0.y*w0[1]; Q1 += A0.y*w1[1];     \
    Q0 += A0.z*w0[2]; Q1 += A0.z*w1[2];     \
    Q0 += A0.w*w0[3]; Q1 += A0.w*w1[3];     \
    Q0 += A1.x*w0[4]; Q1 += A1.x*w1[4];     \
    Q0 += A1.y*w0[5]; Q1 += A1.y*w1[5];     \
    Q0 += A1.z*w0[6]; Q1 += A1.z*w1[6];     \
    Q0 += A1.w*w0[7]; Q1 += A1.w*w1[7];     \
    Q0 += A2X*w0[8];  Q1 += A2X*w1[8];

__global__ __launch_bounds__(256) void k_gather(const float* __restrict__ h,
        const unsigned short* __restrict__ hb,
        const int* __restrict__ off, const float4* __restrict__ rec,
        const float* __restrict__ cWl, const float* __restrict__ cBl,
        unsigned short* __restrict__ aggb1, unsigned short* __restrict__ aggb2,
        int n, int nblk1){
    int b = blockIdx.x;
    int br = (b >= nblk1) ? 1 : 0;
    int node = (br ? b - nblk1 : b)*4 + (threadIdx.x>>6);
    if (node >= n) return;
    int c = (threadIdx.x & 63)*2;
    const float* cW = cWl + br*(9*HH);
    const float* cB = cBl + br*HH;
    unsigned short* aggp = br ? aggb2 : aggb1;

    float w0[9], w1[9];
    #pragma unroll
    for (int k=0;k<9;k++){
        float2 t = *(const float2*)(cW + k*HH + c);
        w0[k]=t.x; w1[k]=t.y;
    }
    float2 cb = *(const float2*)(cB + c);
    float2 acc;
    if (h){
        acc = *(const float2*)(h + (size_t)node*HH + c);
    } else {
        unsigned u = *(const unsigned*)(hb + (size_t)node*HH + c);
        acc.x = __uint_as_float(u<<16); acc.y = __uint_as_float(u & 0xFFFF0000u);
    }

    int slot = node + br*n;
    int lo = off[slot], hi = off[slot+1];
    lo = __builtin_amdgcn_readfirstlane(lo);
    hi = __builtin_amdgcn_readfirstlane(hi);

    const float4* rp = rec + (size_t)lo*3;
    int p = lo;
    for (; p+2<=hi; p+=2, rp+=6){
        float4 e0a = rp[0], e0b = rp[1], e0c = rp[2];
        float4 e1a = rp[3], e1b = rp[4], e1c = rp[5];
        int s0 = __float_as_int(e0c.y);
        int s1 = __float_as_int(e1c.y);
        unsigned u0 = *(const unsigned*)(hb + (size_t)s0*HH + c);
        unsigned u1 = *(const unsigned*)(hb + (size_t)s1*HH + c);
        float hv0x = __uint_as_float(u0<<16), hv0y = __uint_as_float(u0 & 0xFFFF0000u);
        float hv1x = __uint_as_float(u1<<16), hv1y = __uint_as_float(u1 & 0xFFFF0000u);
        QPAIR(e0a, e0b, e0c.x, q00, q01)
        QPAIR(e1a, e1b, e1c.x, q10, q11)
        acc.x += hv0x * silu_f(q00);
        acc.y += hv0y * silu_f(q01);
        acc.x += hv1x * silu_f(q10);
        acc.y += hv1y * silu_f(q11);
    }
    if (p < hi){
        float4 e0a = rp[0], e0b = rp[1], e0c = rp[2];
        int s0 = __float_as_int(e0c.y);
        unsigned u0 = *(const unsigned*)(hb + (size_t)s0*HH + c);
        float hv0x = __uint_as_float(u0<<16), hv0y = __uint_as_float(u0 & 0xFFFF0000u);
        QPAIR(e0a, e0b, e0c.x, q00, q01)
        acc.x += hv0x * silu_f(q00);
        acc.y += hv0y * silu_f(q01);
    }
    unsigned pk = bf16rne(acc.x) | (bf16rne(acc.y)<<16);
    *(unsigned*)(aggp + (size_t)node*HH + c) = pk;
}

// ---------------- dual-branch node GEMM via MFMA bf16, no LDS, no barriers ----------------
// block = 256 thr = 4 waves; wave handles 16 rows x 128 cols; 64 MFMA/wave.
__global__ __launch_bounds__(256) void k_gemm2m(
        const unsigned short* __restrict__ A1, const unsigned short* __restrict__ A2,
        const unsigned short* __restrict__ Bp0, const unsigned short* __restrict__ Bp1,
        const float* __restrict__ b1, const float* __restrict__ b2,
        const float* __restrict__ g1, const float* __restrict__ g2,
        const float* __restrict__ e1, const float* __restrict__ e2,
        float* __restrict__ C, unsigned short* __restrict__ Cb, int n){
    int tx = threadIdx.x;
    int l = tx & 63, wv = tx >> 6;
    int rb = blockIdx.x*LBM + wv*16;
    int mlo = l & 15, khi = l >> 4;
    int arow = rb + mlo;
    bool ok = arow < n;

    f32x4 acc0[8], acc1[8];
    #pragma unroll
    for (int ct=0;ct<8;ct++){ acc0[ct] = (f32x4)0.f; acc1[ct] = (f32x4)0.f; }

    // branch 0
    {
        short8 af[4];
        const short8* ap = (const short8*)(A1 + (size_t)arow*HH);
        #pragma unroll
        for (int s=0;s<4;s++) af[s] = ok ? ap[s*4 + khi] : (short8)0;
        const short8* bp = (const short8*)Bp0;
        #pragma unroll
        for (int s=0;s<4;s++){
            #pragma unroll
            for (int ct=0;ct<8;ct++){
                short8 bf = bp[s*512 + ct*64 + l];
                acc0[ct] = __builtin_amdgcn_mfma_f32_16x16x32_bf16(af[s], bf, acc0[ct], 0, 0, 0);
            }
        }
    }
    // branch 1
    {
        short8 af[4];
        const short8* ap = (const short8*)(A2 + (size_t)arow*HH);
        #pragma unroll
        for (int s=0;s<4;s++) af[s] = ok ? ap[s*4 + khi] : (short8)0;
        const short8* bp = (const short8*)Bp1;
        #pragma unroll
        for (int s=0;s<4;s++){
            #pragma unroll
            for (int ct=0;ct<8;ct++){
                short8 bf = bp[s*512 + ct*64 + l];
                acc1[ct] = __builtin_amdgcn_mfma_f32_16x16x32_bf16(af[s], bf, acc1[ct], 0, 0, 0);
            }
        }
    }

    // epilogue: D row m = khi*4 + r, col n = ct*16 + mlo
    #pragma unroll
    for (int ct=0;ct<8;ct++){
        int ncol = ct*16 + mlo;
        float bi1 = b1[ncol], ga1 = g1[ncol], bt1 = e1[ncol];
        float bi2 = b2[ncol], ga2 = g2[ncol], bt2 = e2[ncol];
        #pragma unroll
        for (int r=0;r<4;r++){
            int grow = rb + khi*4 + r;
            if (grow < n){
                float xv = acc0[ct][r] + bi1;
                xv = (xv>=0.f)? xv : 0.01f*xv;
                float yv = acc1[ct][r] + bi2;
                yv = (yv>=0.f)? yv : 0.01f*yv;
                float o = (ga1*xv + ga2*yv)*BN_INV + bt1 + bt2;
                if (C) C[(size_t)grow*HH + ncol] = o;
                Cb[(size_t)grow*HH + ncol] = (unsigned short)bf16rne(o);
            }
        }
    }
}

// ---------------- fused pool + FC x3 + head ----------------
static __device__ __forceinline__ int lower_bound_i(const int* __restrict__ a, int n, int key){
    int lo=0, hi=n;
    while (lo<hi){ int m=(lo+hi)>>1; if (a[m]<key) lo=m+1; else hi=m; }
    return lo;
}
__global__ void k_poolfc(const float* __restrict__ h, const unsigned short* __restrict__ hb,
                     const int* __restrict__ batch,
                     const float* __restrict__ fcW, const float* __restrict__ fcB,
                     const float* __restrict__ fbg, const float* __restrict__ fbb,
                     const float* __restrict__ outW, const float* __restrict__ outB,
                     float* __restrict__ out, int n){
    __shared__ float row[HH];
    __shared__ float red[2];
    int g = blockIdx.x, c = threadIdx.x;
    int lo = lower_bound_i(batch, n, g);
    int hi = lower_bound_i(batch, n, g+1);
    float v = 0.f;
    if (h){
        for (int r=lo; r<hi; r++) v += h[(size_t)r*HH + c];
    } else {
        for (int r=lo; r<hi; r++)
            v += __uint_as_float(((unsigned)hb[(size_t)r*HH + c])<<16);
    }
    for (int l=0;l<3;l++){
        row[c] = v; __syncthreads();
        float acc = fcB[l*HH + c];
        const float* W = fcW + (size_t)l*HH*HH;
        #pragma unroll 8
        for (int k=0;k<HH;k++) acc += row[k]*W[k*HH + c];
        acc = (acc>=0.f)? acc : 0.01f*acc;
        v = fbg[l*HH+c]*acc*BN_INV + fbb[l*HH+c];
        __syncthreads();
    }
    float t = v * outW[c];
    #pragma unroll
    for (int o=32;o>0;o>>=1) t += __shfl_down(t, o, 64);
    if ((c&63)==0) red[c>>6] = t;
    __syncthreads();
    if (c==0) out[g] = red[0] + red[1] + outB[0];
}

extern "C" void kernel_launch(void* const* d_in, const int* in_sizes, int n_in,
                              void* d_out, int out_size, void* d_ws, size_t ws_size,
                              hipStream_t stream){
    const float* x      = (const float*)d_in[0];
    const float* pos    = (const float*)d_in[1];
    const float* W_in   = (const float*)d_in[2];
    const float* b_in   = (const float*)d_in[3];
    const float* coordW = (const float*)d_in[4];
    const float* coordB = (const float*)d_in[5];
    const float* nodeW  = (const float*)d_in[6];
    const float* nodeB  = (const float*)d_in[7];
    const float* bnG    = (const float*)d_in[8];
    const float* bnB    = (const float*)d_in[9];
    const float* fcW    = (const float*)d_in[10];
    const float* fcB    = (const float*)d_in[11];
    const float* fcBnG  = (const float*)d_in[12];
    const float* fcBnB  = (const float*)d_in[13];
    const float* outW   = (const float*)d_in[14];
    const float* outB   = (const float*)d_in[15];
    const int* ei1      = (const int*)d_in[16];
    const int* ei2      = (const int*)d_in[17];
    const int* batch    = (const int*)d_in[18];
    const int E1 = in_sizes[16]/2, E2 = in_sizes[17]/2;
    const int n = NN;
    const int n2 = 2*n;
    const int ET = E1 + E2;

    char* w = (char*)d_ws;
    size_t o = 0;
    auto alloc = [&](size_t bytes)->void*{
        void* r = w + o;
        o += (bytes + 255) & ~(size_t)255;
        return r;
    };
    unsigned short* hb    = (unsigned short*)alloc((size_t)n*HH*2);
    unsigned short* hb2   = (unsigned short*)alloc((size_t)n*HH*2);
    unsigned short* aggb1 = (unsigned short*)alloc((size_t)n*HH*2);
    unsigned short* aggb2 = (unsigned short*)alloc((size_t)n*HH*2);
    unsigned short* Bpk   = (unsigned short*)alloc((size_t)6*16384*2);
    int*    off  = (int*)alloc((size_t)(n2+1)*4);
    int*    cnt  = (int*)alloc((size_t)n2*4);   // cnt and cur adjacent -> one memset
    int*    cur  = (int*)alloc((size_t)n2*4);
    float4* rec  = (float4*)alloc((size_t)ET*48);
    int*    bsum = (int*)alloc(1024*4);
    // optional fp32 h ping-pong (self-term + poolfc precision) if workspace allows
    float* h  = nullptr;
    float* h2 = nullptr;
    if (ws_size >= o + 2*((size_t)n*HH*4 + 256)){
        h  = (float*)alloc((size_t)n*HH*4);
        h2 = (float*)alloc((size_t)n*HH*4);
    }
    (void)n_in; (void)out_size;

    int nb2 = (n2+255)/256;

    hipMemsetAsync(cnt, 0, (size_t)2*n2*4, stream);
    k_count<<<(ET+255)/256,256,0,stream>>>(ei1, ei2, E1, E2, n, cnt);
    k_scan1<<<nb2,256,0,stream>>>(cnt, n2, off, bsum);
    k_scan2<<<1,1024,0,stream>>>(bsum, nb2);
    k_scan3<<<nb2,256,0,stream>>>(off, bsum, n2, ET);
    k_fill<<<(ET+255)/256,256,0,stream>>>(ei1, ei2, E1, E2, n, pos, off, cur, rec);
    k_pack<<<48,256,0,stream>>>(nodeW, Bpk);

    k_input<<<2048,256,0,stream>>>(x, W_in, b_in, h, hb);

    int nb4 = (n+3)/4;
    float* hcur = h;  unsigned short* hbcur = hb;
    float* hoth = h2; unsigned short* hboth = hb2;
    for (int l=0; l<3; l++){
        int li0 = l*2, li1 = l*2+1;
        k_gather<<<2*nb4,256,0,stream>>>(hcur, hbcur, off, rec,
            coordW + (size_t)li0*9*HH, coordB + (size_t)li0*HH, aggb1, aggb2, n, nb4);
        k_gemm2m<<<(n+LBM-1)/LBM,256,0,stream>>>(aggb1, aggb2,
            Bpk + (size_t)li0*16384, Bpk + (size_t)li1*16384,
            nodeB + (size_t)li0*HH,  nodeB + (size_t)li1*HH,
            bnG   + (size_t)li0*HH,  bnG   + (size_t)li1*HH,
            bnB   + (size_t)li0*HH,  bnB   + (size_t)li1*HH,
            hoth, hboth, n);
        float* t = hcur; hcur = hoth; hoth = t;
        unsigned short* tb = hbcur; hbcur = hboth; hboth = tb;
    }

    k_poolfc<<<GG,128,0,stream>>>(hcur, hbcur, batch, fcW, fcB, fcBnG, fcBnB, outW, outB, (float*)d_out, n);
}

// Round 11
// 644.539 us; speedup vs baseline: 1.2824x; 1.1389x over previous
//
#include <hip/hip_runtime.h>
#include <math.h>

#define NN   100000
#define HH   128
#define INF_ 35
#define GG   1000
#define LBM  64
#define NBINS 2048
#define DSCALE 128.0f      /* NBINS / 16.0 */
#define DINV   0.0078125f  /* 16.0 / NBINS */
#define DCLAMP 15.992f     /* ensures bin+1 <= 2047 */

typedef __attribute__((ext_vector_type(8))) short short8;
typedef __attribute__((ext_vector_type(4))) float f32x4;

static __device__ __forceinline__ float silu_f(float x){ return x / (1.f + __expf(-x)); }
static __device__ __forceinline__ unsigned bf16rne(float x){
    unsigned u = __float_as_uint(x);
    return (u + 0x7FFFu + ((u>>16)&1u)) >> 16;
}
#define BN_INV 0.9999950000374997f  /* 1/sqrt(1+1e-5) */

// ---------------- stacked CSR build (both graphs, dst' = dst + n*branch) ----------------
__global__ void k_count(const int* __restrict__ ei1, const int* __restrict__ ei2,
                        int E1, int E2, int n, int* __restrict__ deg){
    int e = blockIdx.x*256 + threadIdx.x;
    int ET = E1 + E2;
    if (e >= ET) return;
    int c;
    if (e < E1) c = ei1[E1 + e];
    else        c = n + ei2[E2 + (e - E1)];
    atomicAdd(&deg[c], 1);
}

__global__ void k_scan1(const int* __restrict__ deg, int n2, int* __restrict__ off, int* __restrict__ bsum){
    __shared__ int s[256];
    int tid = threadIdx.x; int i = blockIdx.x*256 + tid;
    int v = (i<n2)? deg[i] : 0;
    s[tid] = v; __syncthreads();
    for (int ofs=1; ofs<256; ofs<<=1){
        int t = (tid>=ofs)? s[tid-ofs] : 0;
        __syncthreads(); s[tid] += t; __syncthreads();
    }
    if (i<n2) off[i] = s[tid] - v;
    if (tid==255) bsum[blockIdx.x] = s[255];
}

__global__ void k_scan2(int* __restrict__ bsum, int nb){
    __shared__ int s[1024];
    int tid = threadIdx.x;
    int v = (tid<nb)? bsum[tid] : 0;
    s[tid] = v; __syncthreads();
    for (int ofs=1; ofs<1024; ofs<<=1){
        int t = (tid>=ofs)? s[tid-ofs] : 0;
        __syncthreads(); s[tid] += t; __syncthreads();
    }
    if (tid<nb) bsum[tid] = s[tid] - v;
}

__global__ void k_scan3(int* __restrict__ off, const int* __restrict__ bsum, int n2, int ET){
    int i = blockIdx.x*256 + threadIdx.x;
    if (i<n2) off[i] += bsum[i>>8];
    if (i==0) off[n2] = ET;
}

// fill stacked CSR records: {src, d} = 8B
__global__ void k_fill(const int* __restrict__ ei1, const int* __restrict__ ei2,
                       int E1, int E2, int n, const float* __restrict__ pos,
                       const int* __restrict__ off, int* __restrict__ cur,
                       float2* __restrict__ rec){
    int e = blockIdx.x*256 + threadIdx.x;
    int ET = E1 + E2;
    if (e >= ET) return;
    int r, creal, cslot;
    if (e < E1){ r = ei1[e];        creal = ei1[E1 + e];        cslot = creal; }
    else       { int ee = e - E1; r = ei2[ee]; creal = ei2[E2 + ee]; cslot = n + creal; }
    int slot = atomicAdd(&cur[cslot], 1);
    int p = off[cslot] + slot;
    float dx = pos[r*3+0]-pos[creal*3+0];
    float dy = pos[r*3+1]-pos[creal*3+1];
    float dz = pos[r*3+2]-pos[creal*3+2];
    float d  = sqrtf(dx*dx + dy*dy + dz*dz);
    rec[p] = make_float2(__int_as_float(r), d);
}

// ---------------- radial tables: tab[li][bin][col] = silu(rbf(bin*DINV)@cW[li] + cB[li]) ----------------
__global__ void k_table(const float* __restrict__ coordW, const float* __restrict__ coordB,
                        float* __restrict__ tabs){
    int idx = blockIdx.x*256 + threadIdx.x;       // 6*NBINS*128
    if (idx >= 6*NBINS*HH) return;
    int li  = idx / (NBINS*HH);
    int rem = idx - li*(NBINS*HH);
    int bin = rem >> 7;
    int col = rem & 127;
    float d = (float)bin * DINV;
    const float* cW = coordW + (size_t)li*9*HH;
    float q = coordB[li*HH + col];
    #pragma unroll
    for (int k=0;k<9;k++){
        float t = 1.5f*d - 1.125f*(float)k;
        q += __expf(-t*t) * cW[k*HH + col];
    }
    tabs[idx] = silu_f(q);
}

// ---------------- pack nodeW (6 matrices) into MFMA B-fragment layout, bf16 ----------------
__global__ void k_pack(const float* __restrict__ nodeW, unsigned short* __restrict__ Bpk){
    int idx = blockIdx.x*256 + threadIdx.x;          // 6*2048 = 12288
    if (idx >= 6*2048) return;
    int li = idx >> 11;
    int r  = idx & 2047;
    int s  = r >> 9;
    int r2 = r & 511;
    int ct = r2 >> 6;
    int l  = r2 & 63;
    const float* src = nodeW + (size_t)li*16384 + (size_t)(s*32 + (l>>4)*8)*HH + ct*16 + (l&15);
    unsigned short o[8];
    #pragma unroll
    for (int j=0;j<8;j++) o[j] = (unsigned short)bf16rne(src[(size_t)j*HH]);
    uint4 v;
    v.x = o[0] | ((unsigned)o[1]<<16);
    v.y = o[2] | ((unsigned)o[3]<<16);
    v.z = o[4] | ((unsigned)o[5]<<16);
    v.w = o[6] | ((unsigned)o[7]<<16);
    *(uint4*)(Bpk + (size_t)idx*8) = v;
}

// ---------------- input: h = silu(x @ W_in + b), fp32 (optional) + bf16 mirror ----------------
#define NT_IN (NN/16)
__global__ __launch_bounds__(256) void k_input(const float* __restrict__ x, const float* __restrict__ W,
                        const float* __restrict__ b, float* __restrict__ h,
                        unsigned short* __restrict__ hb){
    __shared__ __align__(16) float xs[16][36];
    int tx = threadIdx.x;
    int c = tx & 127, g = tx >> 7;
    float4 wv[9];
    {
        float* wf = (float*)wv;
        #pragma unroll
        for (int k=0;k<INF_;k++) wf[k] = W[k*HH + c];
        wf[35] = 0.f;
    }
    float bc = b[c];
    for (int tile = blockIdx.x; tile < NT_IN; tile += gridDim.x){
        int r0 = tile*16;
        for (int i = tx; i < 16*INF_; i += 256){
            int rr = i/INF_, kk = i - rr*INF_;
            xs[rr][kk] = x[(size_t)(r0+rr)*INF_ + kk];
        }
        if (tx < 16) xs[tx][35] = 0.f;
        __syncthreads();
        float acc[8];
        #pragma unroll
        for (int j=0;j<8;j++) acc[j] = bc;
        #pragma unroll
        for (int kk=0;kk<9;kk++){
            float4 w4 = wv[kk];
            #pragma unroll
            for (int j=0;j<8;j++){
                float4 xv = *(const float4*)(&xs[g*8+j][kk*4]);
                acc[j] += xv.x*w4.x + xv.y*w4.y + xv.z*w4.z + xv.w*w4.w;
            }
        }
        #pragma unroll
        for (int j=0;j<8;j++){
            int gr = r0 + g*8 + j;
            float v = silu_f(acc[j]);
            if (h) h[(size_t)gr*HH + c] = v;
            hb[(size_t)gr*HH + c] = (unsigned short)bf16rne(v);
        }
        __syncthreads();
    }
}

// ---------------- merged dual-branch gather: table-lookup radial, bf16 h, bf16 agg out ----------------
__global__ __launch_bounds__(256) void k_gather(const float* __restrict__ h,
        const unsigned short* __restrict__ hb,
        const int* __restrict__ off, const float2* __restrict__ rec,
        const float* __restrict__ tab0, const float* __restrict__ tab1,
        unsigned short* __restrict__ aggb1, unsigned short* __restrict__ aggb2,
        int n, int nblk1){
    int b = blockIdx.x;
    int br = (b >= nblk1) ? 1 : 0;
    int node = (br ? b - nblk1 : b)*4 + (threadIdx.x>>6);
    if (node >= n) return;
    int c = (threadIdx.x & 63)*2;
    const float* tab = br ? tab1 : tab0;
    unsigned short* aggp = br ? aggb2 : aggb1;

    float2 acc;
    if (h){
        acc = *(const float2*)(h + (size_t)node*HH + c);
    } else {
        unsigned u = *(const unsigned*)(hb + (size_t)node*HH + c);
        acc.x = __uint_as_float(u<<16); acc.y = __uint_as_float(u & 0xFFFF0000u);
    }

    int slot = node + br*n;
    int lo = off[slot], hi = off[slot+1];
    lo = __builtin_amdgcn_readfirstlane(lo);
    hi = __builtin_amdgcn_readfirstlane(hi);

    int p = lo;
    for (; p+2<=hi; p+=2){
        float2 r0 = rec[p], r1 = rec[p+1];
        int s0 = __float_as_int(r0.x);
        int s1 = __float_as_int(r1.x);
        float db0 = fminf(r0.y, DCLAMP)*DSCALE;
        float db1 = fminf(r1.y, DCLAMP)*DSCALE;
        int b0 = (int)db0; float f0 = db0 - (float)b0;
        int b1 = (int)db1; float f1 = db1 - (float)b1;
        unsigned u0 = *(const unsigned*)(hb + (size_t)s0*HH + c);
        unsigned u1 = *(const unsigned*)(hb + (size_t)s1*HH + c);
        float2 ta0 = *(const float2*)(tab + (size_t)b0*HH + c);
        float2 tb0 = *(const float2*)(tab + (size_t)(b0+1)*HH + c);
        float2 ta1 = *(const float2*)(tab + (size_t)b1*HH + c);
        float2 tb1 = *(const float2*)(tab + (size_t)(b1+1)*HH + c);
        float hv0x = __uint_as_float(u0<<16), hv0y = __uint_as_float(u0 & 0xFFFF0000u);
        float hv1x = __uint_as_float(u1<<16), hv1y = __uint_as_float(u1 & 0xFFFF0000u);
        float q00 = ta0.x + (tb0.x - ta0.x)*f0;
        float q01 = ta0.y + (tb0.y - ta0.y)*f0;
        float q10 = ta1.x + (tb1.x - ta1.x)*f1;
        float q11 = ta1.y + (tb1.y - ta1.y)*f1;
        acc.x += hv0x * q00;
        acc.y += hv0y * q01;
        acc.x += hv1x * q10;
        acc.y += hv1y * q11;
    }
    if (p < hi){
        float2 r0 = rec[p];
        int s0 = __float_as_int(r0.x);
        float db0 = fminf(r0.y, DCLAMP)*DSCALE;
        int b0 = (int)db0; float f0 = db0 - (float)b0;
        unsigned u0 = *(const unsigned*)(hb + (size_t)s0*HH + c);
        float2 ta0 = *(const float2*)(tab + (size_t)b0*HH + c);
        float2 tb0 = *(const float2*)(tab + (size_t)(b0+1)*HH + c);
        float hv0x = __uint_as_float(u0<<16), hv0y = __uint_as_float(u0 & 0xFFFF0000u);
        float q00 = ta0.x + (tb0.x - ta0.x)*f0;
        float q01 = ta0.y + (tb0.y - ta0.y)*f0;
        acc.x += hv0x * q00;
        acc.y += hv0y * q01;
    }
    unsigned pk = bf16rne(acc.x) | (bf16rne(acc.y)<<16);
    *(unsigned*)(aggp + (size_t)node*HH + c) = pk;
}

// ---------------- dual-branch node GEMM via MFMA bf16, no LDS, no barriers ----------------
__global__ __launch_bounds__(256) void k_gemm2m(
        const unsigned short* __restrict__ A1, const unsigned short* __restrict__ A2,
        const unsigned short* __restrict__ Bp0, const unsigned short* __restrict__ Bp1,
        const float* __restrict__ b1, const float* __restrict__ b2,
        const float* __restrict__ g1, const float* __restrict__ g2,
        const float* __restrict__ e1, const float* __restrict__ e2,
        float* __restrict__ C, unsigned short* __restrict__ Cb, int n){
    int tx = threadIdx.x;
    int l = tx & 63, wv = tx >> 6;
    int rb = blockIdx.x*LBM + wv*16;
    int mlo = l & 15, khi = l >> 4;
    int arow = rb + mlo;
    bool ok = arow < n;

    f32x4 acc0[8], acc1[8];
    #pragma unroll
    for (int ct=0;ct<8;ct++){ acc0[ct] = (f32x4)0.f; acc1[ct] = (f32x4)0.f; }

    {
        short8 af[4];
        const short8* ap = (const short8*)(A1 + (size_t)arow*HH);
        #pragma unroll
        for (int s=0;s<4;s++) af[s] = ok ? ap[s*4 + khi] : (short8)0;
        const short8* bp = (const short8*)Bp0;
        #pragma unroll
        for (int s=0;s<4;s++){
            #pragma unroll
            for (int ct=0;ct<8;ct++){
                short8 bf = bp[s*512 + ct*64 + l];
                acc0[ct] = __builtin_amdgcn_mfma_f32_16x16x32_bf16(af[s], bf, acc0[ct], 0, 0, 0);
            }
        }
    }
    {
        short8 af[4];
        const short8* ap = (const short8*)(A2 + (size_t)arow*HH);
        #pragma unroll
        for (int s=0;s<4;s++) af[s] = ok ? ap[s*4 + khi] : (short8)0;
        const short8* bp = (const short8*)Bp1;
        #pragma unroll
        for (int s=0;s<4;s++){
            #pragma unroll
            for (int ct=0;ct<8;ct++){
                short8 bf = bp[s*512 + ct*64 + l];
                acc1[ct] = __builtin_amdgcn_mfma_f32_16x16x32_bf16(af[s], bf, acc1[ct], 0, 0, 0);
            }
        }
    }

    #pragma unroll
    for (int ct=0;ct<8;ct++){
        int ncol = ct*16 + mlo;
        float bi1 = b1[ncol], ga1 = g1[ncol], bt1 = e1[ncol];
        float bi2 = b2[ncol], ga2 = g2[ncol], bt2 = e2[ncol];
        #pragma unroll
        for (int r=0;r<4;r++){
            int grow = rb + khi*4 + r;
            if (grow < n){
                float xv = acc0[ct][r] + bi1;
                xv = (xv>=0.f)? xv : 0.01f*xv;
                float yv = acc1[ct][r] + bi2;
                yv = (yv>=0.f)? yv : 0.01f*yv;
                float o = (ga1*xv + ga2*yv)*BN_INV + bt1 + bt2;
                if (C) C[(size_t)grow*HH + ncol] = o;
                Cb[(size_t)grow*HH + ncol] = (unsigned short)bf16rne(o);
            }
        }
    }
}

// ---------------- fused pool + FC x3 + head ----------------
static __device__ __forceinline__ int lower_bound_i(const int* __restrict__ a, int n, int key){
    int lo=0, hi=n;
    while (lo<hi){ int m=(lo+hi)>>1; if (a[m]<key) lo=m+1; else hi=m; }
    return lo;
}
__global__ void k_poolfc(const float* __restrict__ h, const unsigned short* __restrict__ hb,
                     const int* __restrict__ batch,
                     const float* __restrict__ fcW, const float* __restrict__ fcB,
                     const float* __restrict__ fbg, const float* __restrict__ fbb,
                     const float* __restrict__ outW, const float* __restrict__ outB,
                     float* __restrict__ out, int n){
    __shared__ float row[HH];
    __shared__ float red[2];
    int g = blockIdx.x, c = threadIdx.x;
    int lo = lower_bound_i(batch, n, g);
    int hi = lower_bound_i(batch, n, g+1);
    float v = 0.f;
    if (h){
        for (int r=lo; r<hi; r++) v += h[(size_t)r*HH + c];
    } else {
        for (int r=lo; r<hi; r++)
            v += __uint_as_float(((unsigned)hb[(size_t)r*HH + c])<<16);
    }
    for (int l=0;l<3;l++){
        row[c] = v; __syncthreads();
        float acc = fcB[l*HH + c];
        const float* W = fcW + (size_t)l*HH*HH;
        #pragma unroll 8
        for (int k=0;k<HH;k++) acc += row[k]*W[k*HH + c];
        acc = (acc>=0.f)? acc : 0.01f*acc;
        v = fbg[l*HH+c]*acc*BN_INV + fbb[l*HH+c];
        __syncthreads();
    }
    float t = v * outW[c];
    #pragma unroll
    for (int o=32;o>0;o>>=1) t += __shfl_down(t, o, 64);
    if ((c&63)==0) red[c>>6] = t;
    __syncthreads();
    if (c==0) out[g] = red[0] + red[1] + outB[0];
}

extern "C" void kernel_launch(void* const* d_in, const int* in_sizes, int n_in,
                              void* d_out, int out_size, void* d_ws, size_t ws_size,
                              hipStream_t stream){
    const float* x      = (const float*)d_in[0];
    const float* pos    = (const float*)d_in[1];
    const float* W_in   = (const float*)d_in[2];
    const float* b_in   = (const float*)d_in[3];
    const float* coordW = (const float*)d_in[4];
    const float* coordB = (const float*)d_in[5];
    const float* nodeW  = (const float*)d_in[6];
    const float* nodeB  = (const float*)d_in[7];
    const float* bnG    = (const float*)d_in[8];
    const float* bnB    = (const float*)d_in[9];
    const float* fcW    = (const float*)d_in[10];
    const float* fcB    = (const float*)d_in[11];
    const float* fcBnG  = (const float*)d_in[12];
    const float* fcBnB  = (const float*)d_in[13];
    const float* outW   = (const float*)d_in[14];
    const float* outB   = (const float*)d_in[15];
    const int* ei1      = (const int*)d_in[16];
    const int* ei2      = (const int*)d_in[17];
    const int* batch    = (const int*)d_in[18];
    const int E1 = in_sizes[16]/2, E2 = in_sizes[17]/2;
    const int n = NN;
    const int n2 = 2*n;
    const int ET = E1 + E2;

    char* w = (char*)d_ws;
    size_t o = 0;
    auto alloc = [&](size_t bytes)->void*{
        void* r = w + o;
        o += (bytes + 255) & ~(size_t)255;
        return r;
    };
    unsigned short* hb    = (unsigned short*)alloc((size_t)n*HH*2);
    unsigned short* hb2   = (unsigned short*)alloc((size_t)n*HH*2);
    unsigned short* aggb1 = (unsigned short*)alloc((size_t)n*HH*2);
    unsigned short* aggb2 = (unsigned short*)alloc((size_t)n*HH*2);
    unsigned short* Bpk   = (unsigned short*)alloc((size_t)6*16384*2);
    float*  tabs = (float*)alloc((size_t)6*NBINS*HH*4);
    int*    off  = (int*)alloc((size_t)(n2+1)*4);
    int*    cnt  = (int*)alloc((size_t)n2*4);   // cnt and cur adjacent -> one memset
    int*    cur  = (int*)alloc((size_t)n2*4);
    float2* rec  = (float2*)alloc((size_t)ET*8);
    int*    bsum = (int*)alloc(1024*4);
    // optional fp32 buffers: h (input, layer0 self-term) + hfin (layer2 out, poolfc)
    float* h    = nullptr;
    float* hfin = nullptr;
    if (ws_size >= o + 2*((size_t)n*HH*4 + 256)){
        h    = (float*)alloc((size_t)n*HH*4);
        hfin = (float*)alloc((size_t)n*HH*4);
    }
    (void)n_in; (void)out_size;

    int nb2 = (n2+255)/256;

    hipMemsetAsync(cnt, 0, (size_t)2*n2*4, stream);
    k_count<<<(ET+255)/256,256,0,stream>>>(ei1, ei2, E1, E2, n, cnt);
    k_scan1<<<nb2,256,0,stream>>>(cnt, n2, off, bsum);
    k_scan2<<<1,1024,0,stream>>>(bsum, nb2);
    k_scan3<<<nb2,256,0,stream>>>(off, bsum, n2, ET);
    k_fill<<<(ET+255)/256,256,0,stream>>>(ei1, ei2, E1, E2, n, pos, off, cur, rec);
    k_pack<<<48,256,0,stream>>>(nodeW, Bpk);
    k_table<<<(6*NBINS*HH+255)/256,256,0,stream>>>(coordW, coordB, tabs);

    k_input<<<2048,256,0,stream>>>(x, W_in, b_in, h, hb);

    int nb4 = (n+3)/4;
    unsigned short* hbcur = hb;
    unsigned short* hboth = hb2;
    for (int l=0; l<3; l++){
        int li0 = l*2, li1 = l*2+1;
        const float* hself = (l==0) ? h : nullptr;   // layers 1,2: self-term from bf16 mirror
        float* Cout = (l==2) ? hfin : nullptr;       // fp32 out only on final layer (poolfc)
        k_gather<<<2*nb4,256,0,stream>>>(hself, hbcur, off, rec,
            tabs + (size_t)li0*NBINS*HH, tabs + (size_t)li1*NBINS*HH,
            aggb1, aggb2, n, nb4);
        k_gemm2m<<<(n+LBM-1)/LBM,256,0,stream>>>(aggb1, aggb2,
            Bpk + (size_t)li0*16384, Bpk + (size_t)li1*16384,
            nodeB + (size_t)li0*HH,  nodeB + (size_t)li1*HH,
            bnG   + (size_t)li0*HH,  bnG   + (size_t)li1*HH,
            bnB   + (size_t)li0*HH,  bnB   + (size_t)li1*HH,
            Cout, hboth, n);
        unsigned short* tb = hbcur; hbcur = hboth; hboth = tb;
    }

    k_poolfc<<<GG,128,0,stream>>>(hfin, hbcur, batch, fcW, fcB, fcBnG, fcBnB, outW, outB, (float*)d_out, n);
}

// Round 12
// 572.070 us; speedup vs baseline: 1.4448x; 1.1267x over previous
//
#include <hip/hip_runtime.h>
#include <math.h>

#define NN   100000
#define HH   128
#define INF_ 35
#define GG   1000
#define LBM  64
#define NBINS 2048
#define DSCALE 128.0f      /* NBINS / 16.0 */
#define DINV   0.0078125f  /* 16.0 / NBINS */
#define DCLAMP 15.992f     /* ensures bin+1 <= 2047 */

typedef __attribute__((ext_vector_type(8))) short short8;
typedef __attribute__((ext_vector_type(4))) float f32x4;

static __device__ __forceinline__ float silu_f(float x){ return x / (1.f + __expf(-x)); }
static __device__ __forceinline__ unsigned bf16rne(float x){
    unsigned u = __float_as_uint(x);
    return (u + 0x7FFFu + ((u>>16)&1u)) >> 16;
}
#define BN_INV 0.9999950000374997f  /* 1/sqrt(1+1e-5) */

// ---------------- stacked CSR build (both graphs, dst' = dst + n*branch) ----------------
__global__ void k_count(const int* __restrict__ ei1, const int* __restrict__ ei2,
                        int E1, int E2, int n, int* __restrict__ deg){
    int e = blockIdx.x*256 + threadIdx.x;
    int ET = E1 + E2;
    if (e >= ET) return;
    int c;
    if (e < E1) c = ei1[E1 + e];
    else        c = n + ei2[E2 + (e - E1)];
    atomicAdd(&deg[c], 1);
}

__global__ void k_scan1(const int* __restrict__ deg, int n2, int* __restrict__ off, int* __restrict__ bsum){
    __shared__ int s[256];
    int tid = threadIdx.x; int i = blockIdx.x*256 + tid;
    int v = (i<n2)? deg[i] : 0;
    s[tid] = v; __syncthreads();
    for (int ofs=1; ofs<256; ofs<<=1){
        int t = (tid>=ofs)? s[tid-ofs] : 0;
        __syncthreads(); s[tid] += t; __syncthreads();
    }
    if (i<n2) off[i] = s[tid] - v;
    if (tid==255) bsum[blockIdx.x] = s[255];
}

__global__ void k_scan2(int* __restrict__ bsum, int nb){
    __shared__ int s[1024];
    int tid = threadIdx.x;
    int v = (tid<nb)? bsum[tid] : 0;
    s[tid] = v; __syncthreads();
    for (int ofs=1; ofs<1024; ofs<<=1){
        int t = (tid>=ofs)? s[tid-ofs] : 0;
        __syncthreads(); s[tid] += t; __syncthreads();
    }
    if (tid<nb) bsum[tid] = s[tid] - v;
}

__global__ void k_scan3(int* __restrict__ off, const int* __restrict__ bsum, int n2, int ET){
    int i = blockIdx.x*256 + threadIdx.x;
    if (i<n2) off[i] += bsum[i>>8];
    if (i==0) off[n2] = ET;
}

// fill stacked CSR records: {src, d} = 8B
__global__ void k_fill(const int* __restrict__ ei1, const int* __restrict__ ei2,
                       int E1, int E2, int n, const float* __restrict__ pos,
                       const int* __restrict__ off, int* __restrict__ cur,
                       float2* __restrict__ rec){
    int e = blockIdx.x*256 + threadIdx.x;
    int ET = E1 + E2;
    if (e >= ET) return;
    int r, creal, cslot;
    if (e < E1){ r = ei1[e];        creal = ei1[E1 + e];        cslot = creal; }
    else       { int ee = e - E1; r = ei2[ee]; creal = ei2[E2 + ee]; cslot = n + creal; }
    int slot = atomicAdd(&cur[cslot], 1);
    int p = off[cslot] + slot;
    float dx = pos[r*3+0]-pos[creal*3+0];
    float dy = pos[r*3+1]-pos[creal*3+1];
    float dz = pos[r*3+2]-pos[creal*3+2];
    float d  = sqrtf(dx*dx + dy*dy + dz*dz);
    rec[p] = make_float2(__int_as_float(r), d);
}

// ---------------- fused prep: nodeW MFMA-pack + radial tables + transposed W_in ----------------
// blocks [0,48): pack ; [48,66): Wtg ; [66, 66+6144): table
__global__ void k_prep(const float* __restrict__ nodeW,
                       const float* __restrict__ coordW, const float* __restrict__ coordB,
                       const float* __restrict__ W_in,
                       unsigned short* __restrict__ Bpk, float* __restrict__ tabs,
                       float* __restrict__ Wtg){
    int blk = blockIdx.x, tx = threadIdx.x;
    if (blk < 48){
        int idx = blk*256 + tx;                  // < 12288
        if (idx >= 6*2048) return;
        int li = idx >> 11;
        int r  = idx & 2047;
        int s  = r >> 9;
        int r2 = r & 511;
        int ct = r2 >> 6;
        int l  = r2 & 63;
        const float* src = nodeW + (size_t)li*16384 + (size_t)(s*32 + (l>>4)*8)*HH + ct*16 + (l&15);
        unsigned short o[8];
        #pragma unroll
        for (int j=0;j<8;j++) o[j] = (unsigned short)bf16rne(src[(size_t)j*HH]);
        uint4 v;
        v.x = o[0] | ((unsigned)o[1]<<16);
        v.y = o[2] | ((unsigned)o[3]<<16);
        v.z = o[4] | ((unsigned)o[5]<<16);
        v.w = o[6] | ((unsigned)o[7]<<16);
        *(uint4*)(Bpk + (size_t)idx*8) = v;
    } else if (blk < 66){
        int i = (blk-48)*256 + tx;               // < 4608
        if (i >= 128*36) return;
        int c = i/36, k = i - c*36;
        Wtg[i] = (k < INF_) ? W_in[k*HH + c] : 0.f;
    } else {
        int idx = (blk-66)*256 + tx;             // < 1572864
        if (idx >= 6*NBINS*HH) return;
        int li  = idx / (NBINS*HH);
        int rem = idx - li*(NBINS*HH);
        int bin = rem >> 7;
        int col = rem & 127;
        float d = (float)bin * DINV;
        const float* cW = coordW + (size_t)li*9*HH;
        float q = coordB[li*HH + col];
        #pragma unroll
        for (int k=0;k<9;k++){
            float t = 1.5f*d - 1.125f*(float)k;
            q += __expf(-t*t) * cW[k*HH + col];
        }
        tabs[idx] = silu_f(q);
    }
}

// ---------------- input: hb = bf16(silu(x @ W_in + b)); W streamed from L2 ----------------
#define NT_IN (NN/16)
__global__ __launch_bounds__(256) void k_input(const float* __restrict__ x,
        const float* __restrict__ Wtg, const float* __restrict__ b,
        unsigned short* __restrict__ hb){
    __shared__ __align__(16) float xs[16][36];
    int tx = threadIdx.x;
    int c = tx & 127, g = tx >> 7;
    float bc = b[c];
    const float4* wp = (const float4*)(Wtg + c*36);
    for (int tile = blockIdx.x; tile < NT_IN; tile += gridDim.x){
        int r0 = tile*16;
        for (int i = tx; i < 16*INF_; i += 256){
            int rr = i/INF_, kk = i - rr*INF_;
            xs[rr][kk] = x[(size_t)(r0+rr)*INF_ + kk];
        }
        if (tx < 16) xs[tx][35] = 0.f;
        __syncthreads();
        float acc[8];
        #pragma unroll
        for (int j=0;j<8;j++) acc[j] = bc;
        #pragma unroll
        for (int kk=0;kk<9;kk++){
            float4 w4 = wp[kk];
            #pragma unroll
            for (int j=0;j<8;j++){
                float4 xv = *(const float4*)(&xs[g*8+j][kk*4]);
                acc[j] += xv.x*w4.x + xv.y*w4.y + xv.z*w4.z + xv.w*w4.w;
            }
        }
        #pragma unroll
        for (int j=0;j<8;j++){
            int gr = r0 + g*8 + j;
            hb[(size_t)gr*HH + c] = (unsigned short)bf16rne(silu_f(acc[j]));
        }
        __syncthreads();
    }
}

// ---------------- merged dual-branch gather: table radial, bf16 h, 4-edge unroll ----------------
#define GEDGE(RP, S_, B_, F_)                                        \
    int S_ = __float_as_int((RP).x);                                 \
    float db_##S_ = fminf((RP).y, DCLAMP)*DSCALE;                    \
    int B_ = (int)db_##S_; float F_ = db_##S_ - (float)B_;

__global__ __launch_bounds__(256) void k_gather(
        const unsigned short* __restrict__ hb,
        const int* __restrict__ off, const float2* __restrict__ rec,
        const float* __restrict__ tab0, const float* __restrict__ tab1,
        unsigned short* __restrict__ aggb1, unsigned short* __restrict__ aggb2,
        int n, int nblk1){
    int b = blockIdx.x;
    int br = (b >= nblk1) ? 1 : 0;
    int node = (br ? b - nblk1 : b)*4 + (threadIdx.x>>6);
    if (node >= n) return;
    int c = (threadIdx.x & 63)*2;
    const float* tab = br ? tab1 : tab0;
    unsigned short* aggp = br ? aggb2 : aggb1;

    float2 acc;
    {
        unsigned u = *(const unsigned*)(hb + (size_t)node*HH + c);
        acc.x = __uint_as_float(u<<16); acc.y = __uint_as_float(u & 0xFFFF0000u);
    }

    int slot = node + br*n;
    int lo = off[slot], hi = off[slot+1];
    lo = __builtin_amdgcn_readfirstlane(lo);
    hi = __builtin_amdgcn_readfirstlane(hi);

    int p = lo;
    for (; p+4<=hi; p+=4){
        float2 r0 = rec[p], r1 = rec[p+1], r2 = rec[p+2], r3 = rec[p+3];
        GEDGE(r0, s0, b0, f0)
        GEDGE(r1, s1, b1, f1)
        GEDGE(r2, s2, b2, f2)
        GEDGE(r3, s3, b3, f3)
        unsigned u0 = *(const unsigned*)(hb + (size_t)s0*HH + c);
        unsigned u1 = *(const unsigned*)(hb + (size_t)s1*HH + c);
        unsigned u2 = *(const unsigned*)(hb + (size_t)s2*HH + c);
        unsigned u3 = *(const unsigned*)(hb + (size_t)s3*HH + c);
        float2 ta0 = *(const float2*)(tab + (size_t)b0*HH + c);
        float2 tb0 = *(const float2*)(tab + (size_t)(b0+1)*HH + c);
        float2 ta1 = *(const float2*)(tab + (size_t)b1*HH + c);
        float2 tb1 = *(const float2*)(tab + (size_t)(b1+1)*HH + c);
        float2 ta2 = *(const float2*)(tab + (size_t)b2*HH + c);
        float2 tb2 = *(const float2*)(tab + (size_t)(b2+1)*HH + c);
        float2 ta3 = *(const float2*)(tab + (size_t)b3*HH + c);
        float2 tb3 = *(const float2*)(tab + (size_t)(b3+1)*HH + c);
        acc.x += __uint_as_float(u0<<16)          * (ta0.x + (tb0.x - ta0.x)*f0);
        acc.y += __uint_as_float(u0 & 0xFFFF0000u)* (ta0.y + (tb0.y - ta0.y)*f0);
        acc.x += __uint_as_float(u1<<16)          * (ta1.x + (tb1.x - ta1.x)*f1);
        acc.y += __uint_as_float(u1 & 0xFFFF0000u)* (ta1.y + (tb1.y - ta1.y)*f1);
        acc.x += __uint_as_float(u2<<16)          * (ta2.x + (tb2.x - ta2.x)*f2);
        acc.y += __uint_as_float(u2 & 0xFFFF0000u)* (ta2.y + (tb2.y - ta2.y)*f2);
        acc.x += __uint_as_float(u3<<16)          * (ta3.x + (tb3.x - ta3.x)*f3);
        acc.y += __uint_as_float(u3 & 0xFFFF0000u)* (ta3.y + (tb3.y - ta3.y)*f3);
    }
    for (; p+2<=hi; p+=2){
        float2 r0 = rec[p], r1 = rec[p+1];
        GEDGE(r0, s0, b0, f0)
        GEDGE(r1, s1, b1, f1)
        unsigned u0 = *(const unsigned*)(hb + (size_t)s0*HH + c);
        unsigned u1 = *(const unsigned*)(hb + (size_t)s1*HH + c);
        float2 ta0 = *(const float2*)(tab + (size_t)b0*HH + c);
        float2 tb0 = *(const float2*)(tab + (size_t)(b0+1)*HH + c);
        float2 ta1 = *(const float2*)(tab + (size_t)b1*HH + c);
        float2 tb1 = *(const float2*)(tab + (size_t)(b1+1)*HH + c);
        acc.x += __uint_as_float(u0<<16)          * (ta0.x + (tb0.x - ta0.x)*f0);
        acc.y += __uint_as_float(u0 & 0xFFFF0000u)* (ta0.y + (tb0.y - ta0.y)*f0);
        acc.x += __uint_as_float(u1<<16)          * (ta1.x + (tb1.x - ta1.x)*f1);
        acc.y += __uint_as_float(u1 & 0xFFFF0000u)* (ta1.y + (tb1.y - ta1.y)*f1);
    }
    if (p < hi){
        float2 r0 = rec[p];
        GEDGE(r0, s0, b0, f0)
        unsigned u0 = *(const unsigned*)(hb + (size_t)s0*HH + c);
        float2 ta0 = *(const float2*)(tab + (size_t)b0*HH + c);
        float2 tb0 = *(const float2*)(tab + (size_t)(b0+1)*HH + c);
        acc.x += __uint_as_float(u0<<16)          * (ta0.x + (tb0.x - ta0.x)*f0);
        acc.y += __uint_as_float(u0 & 0xFFFF0000u)* (ta0.y + (tb0.y - ta0.y)*f0);
    }
    unsigned pk = bf16rne(acc.x) | (bf16rne(acc.y)<<16);
    *(unsigned*)(aggp + (size_t)node*HH + c) = pk;
}

// ---------------- dual-branch node GEMM via MFMA bf16, no LDS, no barriers ----------------
__global__ __launch_bounds__(256) void k_gemm2m(
        const unsigned short* __restrict__ A1, const unsigned short* __restrict__ A2,
        const unsigned short* __restrict__ Bp0, const unsigned short* __restrict__ Bp1,
        const float* __restrict__ b1, const float* __restrict__ b2,
        const float* __restrict__ g1, const float* __restrict__ g2,
        const float* __restrict__ e1, const float* __restrict__ e2,
        float* __restrict__ C, unsigned short* __restrict__ Cb, int n){
    int tx = threadIdx.x;
    int l = tx & 63, wv = tx >> 6;
    int rb = blockIdx.x*LBM + wv*16;
    int mlo = l & 15, khi = l >> 4;
    int arow = rb + mlo;
    bool ok = arow < n;

    f32x4 acc0[8], acc1[8];
    #pragma unroll
    for (int ct=0;ct<8;ct++){ acc0[ct] = (f32x4)0.f; acc1[ct] = (f32x4)0.f; }

    {
        short8 af[4];
        const short8* ap = (const short8*)(A1 + (size_t)arow*HH);
        #pragma unroll
        for (int s=0;s<4;s++) af[s] = ok ? ap[s*4 + khi] : (short8)0;
        const short8* bp = (const short8*)Bp0;
        #pragma unroll
        for (int s=0;s<4;s++){
            #pragma unroll
            for (int ct=0;ct<8;ct++){
                short8 bf = bp[s*512 + ct*64 + l];
                acc0[ct] = __builtin_amdgcn_mfma_f32_16x16x32_bf16(af[s], bf, acc0[ct], 0, 0, 0);
            }
        }
    }
    {
        short8 af[4];
        const short8* ap = (const short8*)(A2 + (size_t)arow*HH);
        #pragma unroll
        for (int s=0;s<4;s++) af[s] = ok ? ap[s*4 + khi] : (short8)0;
        const short8* bp = (const short8*)Bp1;
        #pragma unroll
        for (int s=0;s<4;s++){
            #pragma unroll
            for (int ct=0;ct<8;ct++){
                short8 bf = bp[s*512 + ct*64 + l];
                acc1[ct] = __builtin_amdgcn_mfma_f32_16x16x32_bf16(af[s], bf, acc1[ct], 0, 0, 0);
            }
        }
    }

    #pragma unroll
    for (int ct=0;ct<8;ct++){
        int ncol = ct*16 + mlo;
        float bi1 = b1[ncol], ga1 = g1[ncol], bt1 = e1[ncol];
        float bi2 = b2[ncol], ga2 = g2[ncol], bt2 = e2[ncol];
        #pragma unroll
        for (int r=0;r<4;r++){
            int grow = rb + khi*4 + r;
            if (grow < n){
                float xv = acc0[ct][r] + bi1;
                xv = (xv>=0.f)? xv : 0.01f*xv;
                float yv = acc1[ct][r] + bi2;
                yv = (yv>=0.f)? yv : 0.01f*yv;
                float o = (ga1*xv + ga2*yv)*BN_INV + bt1 + bt2;
                if (C) C[(size_t)grow*HH + ncol] = o;
                Cb[(size_t)grow*HH + ncol] = (unsigned short)bf16rne(o);
            }
        }
    }
}

// ---------------- fused pool + FC x3 + head ----------------
static __device__ __forceinline__ int lower_bound_i(const int* __restrict__ a, int n, int key){
    int lo=0, hi=n;
    while (lo<hi){ int m=(lo+hi)>>1; if (a[m]<key) lo=m+1; else hi=m; }
    return lo;
}
__global__ void k_poolfc(const float* __restrict__ h,
                     const int* __restrict__ batch,
                     const float* __restrict__ fcW, const float* __restrict__ fcB,
                     const float* __restrict__ fbg, const float* __restrict__ fbb,
                     const float* __restrict__ outW, const float* __restrict__ outB,
                     float* __restrict__ out, int n){
    __shared__ float row[HH];
    __shared__ float red[2];
    int g = blockIdx.x, c = threadIdx.x;
    int lo = lower_bound_i(batch, n, g);
    int hi = lower_bound_i(batch, n, g+1);
    float v = 0.f;
    for (int r=lo; r<hi; r++) v += h[(size_t)r*HH + c];
    for (int l=0;l<3;l++){
        row[c] = v; __syncthreads();
        float acc = fcB[l*HH + c];
        const float* W = fcW + (size_t)l*HH*HH;
        #pragma unroll 8
        for (int k=0;k<HH;k++) acc += row[k]*W[k*HH + c];
        acc = (acc>=0.f)? acc : 0.01f*acc;
        v = fbg[l*HH+c]*acc*BN_INV + fbb[l*HH+c];
        __syncthreads();
    }
    float t = v * outW[c];
    #pragma unroll
    for (int o=32;o>0;o>>=1) t += __shfl_down(t, o, 64);
    if ((c&63)==0) red[c>>6] = t;
    __syncthreads();
    if (c==0) out[g] = red[0] + red[1] + outB[0];
}

extern "C" void kernel_launch(void* const* d_in, const int* in_sizes, int n_in,
                              void* d_out, int out_size, void* d_ws, size_t ws_size,
                              hipStream_t stream){
    const float* x      = (const float*)d_in[0];
    const float* pos    = (const float*)d_in[1];
    const float* W_in   = (const float*)d_in[2];
    const float* b_in   = (const float*)d_in[3];
    const float* coordW = (const float*)d_in[4];
    const float* coordB = (const float*)d_in[5];
    const float* nodeW  = (const float*)d_in[6];
    const float* nodeB  = (const float*)d_in[7];
    const float* bnG    = (const float*)d_in[8];
    const float* bnB    = (const float*)d_in[9];
    const float* fcW    = (const float*)d_in[10];
    const float* fcB    = (const float*)d_in[11];
    const float* fcBnG  = (const float*)d_in[12];
    const float* fcBnB  = (const float*)d_in[13];
    const float* outW   = (const float*)d_in[14];
    const float* outB   = (const float*)d_in[15];
    const int* ei1      = (const int*)d_in[16];
    const int* ei2      = (const int*)d_in[17];
    const int* batch    = (const int*)d_in[18];
    const int E1 = in_sizes[16]/2, E2 = in_sizes[17]/2;
    const int n = NN;
    const int n2 = 2*n;
    const int ET = E1 + E2;

    char* w = (char*)d_ws;
    size_t o = 0;
    auto alloc = [&](size_t bytes)->void*{
        void* r = w + o;
        o += (bytes + 255) & ~(size_t)255;
        return r;
    };
    unsigned short* hb    = (unsigned short*)alloc((size_t)n*HH*2);
    unsigned short* hb2   = (unsigned short*)alloc((size_t)n*HH*2);
    unsigned short* aggb1 = (unsigned short*)alloc((size_t)n*HH*2);
    unsigned short* aggb2 = (unsigned short*)alloc((size_t)n*HH*2);
    unsigned short* Bpk   = (unsigned short*)alloc((size_t)6*16384*2);
    float*  tabs = (float*)alloc((size_t)6*NBINS*HH*4);
    float*  Wtg  = (float*)alloc((size_t)128*36*4);
    int*    off  = (int*)alloc((size_t)(n2+1)*4);
    int*    cnt  = (int*)alloc((size_t)n2*4);   // cnt and cur adjacent -> one memset
    int*    cur  = (int*)alloc((size_t)n2*4);
    float2* rec  = (float2*)alloc((size_t)ET*8);
    int*    bsum = (int*)alloc(1024*4);
    float*  hfin = (float*)alloc((size_t)n*HH*4);
    (void)n_in; (void)out_size; (void)ws_size;

    int nb2 = (n2+255)/256;

    hipMemsetAsync(cnt, 0, (size_t)2*n2*4, stream);
    k_count<<<(ET+255)/256,256,0,stream>>>(ei1, ei2, E1, E2, n, cnt);
    k_scan1<<<nb2,256,0,stream>>>(cnt, n2, off, bsum);
    k_scan2<<<1,1024,0,stream>>>(bsum, nb2);
    k_scan3<<<nb2,256,0,stream>>>(off, bsum, n2, ET);
    k_fill<<<(ET+255)/256,256,0,stream>>>(ei1, ei2, E1, E2, n, pos, off, cur, rec);
    k_prep<<<66+6144,256,0,stream>>>(nodeW, coordW, coordB, W_in, Bpk, tabs, Wtg);

    k_input<<<2048,256,0,stream>>>(x, Wtg, b_in, hb);

    int nb4 = (n+3)/4;
    unsigned short* hbcur = hb;
    unsigned short* hboth = hb2;
    for (int l=0; l<3; l++){
        int li0 = l*2, li1 = l*2+1;
        float* Cout = (l==2) ? hfin : nullptr;       // fp32 out only on final layer (poolfc)
        k_gather<<<2*nb4,256,0,stream>>>(hbcur, off, rec,
            tabs + (size_t)li0*NBINS*HH, tabs + (size_t)li1*NBINS*HH,
            aggb1, aggb2, n, nb4);
        k_gemm2m<<<(n+LBM-1)/LBM,256,0,stream>>>(aggb1, aggb2,
            Bpk + (size_t)li0*16384, Bpk + (size_t)li1*16384,
            nodeB + (size_t)li0*HH,  nodeB + (size_t)li1*HH,
            bnG   + (size_t)li0*HH,  bnG   + (size_t)li1*HH,
            bnB   + (size_t)li0*HH,  bnB   + (size_t)li1*HH,
            Cout, hboth, n);
        unsigned short* tb = hbcur; hbcur = hboth; hboth = tb;
    }

    k_poolfc<<<GG,128,0,stream>>>(hfin, batch, fcW, fcB, fcBnG, fcBnB, outW, outB, (float*)d_out, n);
}

// Round 13
// 550.733 us; speedup vs baseline: 1.5008x; 1.0387x over previous
//
#include <hip/hip_runtime.h>
#include <math.h>

#define NN   100000
#define HH   128
#define INF_ 35
#define GG   1000
#define LBM  64
#define NBINS 2048
#define DSCALE 128.0f      /* NBINS / 16.0 */
#define DINV   0.0078125f  /* 16.0 / NBINS */
#define DCLAMP 15.992f     /* ensures bin <= 2046 */

typedef __attribute__((ext_vector_type(8))) short short8;
typedef __attribute__((ext_vector_type(4))) float f32x4;

static __device__ __forceinline__ float silu_f(float x){ return x / (1.f + __expf(-x)); }
static __device__ __forceinline__ unsigned bf16rne(float x){
    unsigned u = __float_as_uint(x);
    return (u + 0x7FFFu + ((u>>16)&1u)) >> 16;
}
#define BN_INV 0.9999950000374997f  /* 1/sqrt(1+1e-5) */

// ---------------- stacked CSR build (both graphs, dst' = dst + n*branch) ----------------
__global__ void k_count(const int* __restrict__ ei1, const int* __restrict__ ei2,
                        int E1, int E2, int n, int* __restrict__ deg){
    int e = blockIdx.x*256 + threadIdx.x;
    int ET = E1 + E2;
    if (e >= ET) return;
    int c;
    if (e < E1) c = ei1[E1 + e];
    else        c = n + ei2[E2 + (e - E1)];
    atomicAdd(&deg[c], 1);
}

__global__ void k_scan1(const int* __restrict__ deg, int n2, int* __restrict__ off, int* __restrict__ bsum){
    __shared__ int s[256];
    int tid = threadIdx.x; int i = blockIdx.x*256 + tid;
    int v = (i<n2)? deg[i] : 0;
    s[tid] = v; __syncthreads();
    for (int ofs=1; ofs<256; ofs<<=1){
        int t = (tid>=ofs)? s[tid-ofs] : 0;
        __syncthreads(); s[tid] += t; __syncthreads();
    }
    if (i<n2) off[i] = s[tid] - v;
    if (tid==255) bsum[blockIdx.x] = s[255];
}

__global__ void k_scan2(int* __restrict__ bsum, int nb){
    __shared__ int s[1024];
    int tid = threadIdx.x;
    int v = (tid<nb)? bsum[tid] : 0;
    s[tid] = v; __syncthreads();
    for (int ofs=1; ofs<1024; ofs<<=1){
        int t = (tid>=ofs)? s[tid-ofs] : 0;
        __syncthreads(); s[tid] += t; __syncthreads();
    }
    if (tid<nb) bsum[tid] = s[tid] - v;
}

__global__ void k_scan3(int* __restrict__ off, const int* __restrict__ bsum, int n2, int ET){
    int i = blockIdx.x*256 + threadIdx.x;
    if (i<n2) off[i] += bsum[i>>8];
    if (i==0) off[n2] = ET;
}

// fill stacked CSR records: {src, d} = 8B
__global__ void k_fill(const int* __restrict__ ei1, const int* __restrict__ ei2,
                       int E1, int E2, int n, const float* __restrict__ pos,
                       const int* __restrict__ off, int* __restrict__ cur,
                       float2* __restrict__ rec){
    int e = blockIdx.x*256 + threadIdx.x;
    int ET = E1 + E2;
    if (e >= ET) return;
    int r, creal, cslot;
    if (e < E1){ r = ei1[e];        creal = ei1[E1 + e];        cslot = creal; }
    else       { int ee = e - E1; r = ei2[ee]; creal = ei2[E2 + ee]; cslot = n + creal; }
    int slot = atomicAdd(&cur[cslot], 1);
    int p = off[cslot] + slot;
    float dx = pos[r*3+0]-pos[creal*3+0];
    float dy = pos[r*3+1]-pos[creal*3+1];
    float dz = pos[r*3+2]-pos[creal*3+2];
    float d  = sqrtf(dx*dx + dy*dy + dz*dz);
    rec[p] = make_float2(__int_as_float(r), d);
}

// ---------------- fused prep: nodeW MFMA-pack + (value,slope) radial tables + transposed W_in ----------------
// blocks [0,48): pack ; [48,66): Wtg ; [66, 66+6144): table
__global__ void k_prep(const float* __restrict__ nodeW,
                       const float* __restrict__ coordW, const float* __restrict__ coordB,
                       const float* __restrict__ W_in,
                       unsigned short* __restrict__ Bpk, float2* __restrict__ tabs,
                       float* __restrict__ Wtg){
    int blk = blockIdx.x, tx = threadIdx.x;
    if (blk < 48){
        int idx = blk*256 + tx;                  // < 12288
        if (idx >= 6*2048) return;
        int li = idx >> 11;
        int r  = idx & 2047;
        int s  = r >> 9;
        int r2 = r & 511;
        int ct = r2 >> 6;
        int l  = r2 & 63;
        const float* src = nodeW + (size_t)li*16384 + (size_t)(s*32 + (l>>4)*8)*HH + ct*16 + (l&15);
        unsigned short o[8];
        #pragma unroll
        for (int j=0;j<8;j++) o[j] = (unsigned short)bf16rne(src[(size_t)j*HH]);
        uint4 v;
        v.x = o[0] | ((unsigned)o[1]<<16);
        v.y = o[2] | ((unsigned)o[3]<<16);
        v.z = o[4] | ((unsigned)o[5]<<16);
        v.w = o[6] | ((unsigned)o[7]<<16);
        *(uint4*)(Bpk + (size_t)idx*8) = v;
    } else if (blk < 66){
        int i = (blk-48)*256 + tx;               // < 4608
        if (i >= 128*36) return;
        int c = i/36, k = i - c*36;
        Wtg[i] = (k < INF_) ? W_in[k*HH + c] : 0.f;
    } else {
        int idx = (blk-66)*256 + tx;             // < 1572864
        if (idx >= 6*NBINS*HH) return;
        int li  = idx / (NBINS*HH);
        int rem = idx - li*(NBINS*HH);
        int bin = rem >> 7;
        int col = rem & 127;
        float d0 = (float)bin * DINV;
        float d1 = d0 + DINV;
        const float* cW = coordW + (size_t)li*9*HH;
        float cb = coordB[li*HH + col];
        float q0 = cb, q1 = cb;
        #pragma unroll
        for (int k=0;k<9;k++){
            float wk = cW[k*HH + col];
            float t0 = 1.5f*d0 - 1.125f*(float)k;
            float t1 = 1.5f*d1 - 1.125f*(float)k;
            q0 += __expf(-t0*t0) * wk;
            q1 += __expf(-t1*t1) * wk;
        }
        float v = silu_f(q0);
        tabs[idx] = make_float2(v, silu_f(q1) - v);
    }
}

// ---------------- input: hb = bf16(silu(x @ W_in + b)); W streamed from L2 ----------------
#define NT_IN (NN/16)
__global__ __launch_bounds__(256) void k_input(const float* __restrict__ x,
        const float* __restrict__ Wtg, const float* __restrict__ b,
        unsigned short* __restrict__ hb){
    __shared__ __align__(16) float xs[16][36];
    int tx = threadIdx.x;
    int c = tx & 127, g = tx >> 7;
    float bc = b[c];
    const float4* wp = (const float4*)(Wtg + c*36);
    for (int tile = blockIdx.x; tile < NT_IN; tile += gridDim.x){
        int r0 = tile*16;
        for (int i = tx; i < 16*INF_; i += 256){
            int rr = i/INF_, kk = i - rr*INF_;
            xs[rr][kk] = x[(size_t)(r0+rr)*INF_ + kk];
        }
        if (tx < 16) xs[tx][35] = 0.f;
        __syncthreads();
        float acc[8];
        #pragma unroll
        for (int j=0;j<8;j++) acc[j] = bc;
        #pragma unroll
        for (int kk=0;kk<9;kk++){
            float4 w4 = wp[kk];
            #pragma unroll
            for (int j=0;j<8;j++){
                float4 xv = *(const float4*)(&xs[g*8+j][kk*4]);
                acc[j] += xv.x*w4.x + xv.y*w4.y + xv.z*w4.z + xv.w*w4.w;
            }
        }
        #pragma unroll
        for (int j=0;j<8;j++){
            int gr = r0 + g*8 + j;
            hb[(size_t)gr*HH + c] = (unsigned short)bf16rne(silu_f(acc[j]));
        }
        __syncthreads();
    }
}

// ---------------- merged dual-branch gather: (v,slope) table, bf16 h, 4-edge unroll ----------------
#define GEDGE(RP, S_, B_, F_)                                        \
    int S_ = __float_as_int((RP).x);                                 \
    float db_##S_ = fminf((RP).y, DCLAMP)*DSCALE;                    \
    int B_ = (int)db_##S_; float F_ = db_##S_ - (float)B_;

__global__ __launch_bounds__(256) void k_gather(
        const unsigned short* __restrict__ hb,
        const int* __restrict__ off, const float2* __restrict__ rec,
        const float2* __restrict__ tab0, const float2* __restrict__ tab1,
        unsigned short* __restrict__ aggb1, unsigned short* __restrict__ aggb2,
        int n, int nblk1){
    int b = blockIdx.x;
    int br = (b >= nblk1) ? 1 : 0;
    int node = (br ? b - nblk1 : b)*4 + (threadIdx.x>>6);
    if (node >= n) return;
    int c = (threadIdx.x & 63)*2;
    const float2* tab = br ? tab1 : tab0;
    unsigned short* aggp = br ? aggb2 : aggb1;

    float2 acc;
    {
        unsigned u = *(const unsigned*)(hb + (size_t)node*HH + c);
        acc.x = __uint_as_float(u<<16); acc.y = __uint_as_float(u & 0xFFFF0000u);
    }

    int slot = node + br*n;
    int lo = off[slot], hi = off[slot+1];
    lo = __builtin_amdgcn_readfirstlane(lo);
    hi = __builtin_amdgcn_readfirstlane(hi);

    int p = lo;
    for (; p+4<=hi; p+=4){
        float2 r0 = rec[p], r1 = rec[p+1], r2 = rec[p+2], r3 = rec[p+3];
        GEDGE(r0, s0, b0, f0)
        GEDGE(r1, s1, b1, f1)
        GEDGE(r2, s2, b2, f2)
        GEDGE(r3, s3, b3, f3)
        unsigned u0 = *(const unsigned*)(hb + (size_t)s0*HH + c);
        unsigned u1 = *(const unsigned*)(hb + (size_t)s1*HH + c);
        unsigned u2 = *(const unsigned*)(hb + (size_t)s2*HH + c);
        unsigned u3 = *(const unsigned*)(hb + (size_t)s3*HH + c);
        float4 t0 = *(const float4*)(tab + (size_t)b0*HH + c);
        float4 t1 = *(const float4*)(tab + (size_t)b1*HH + c);
        float4 t2 = *(const float4*)(tab + (size_t)b2*HH + c);
        float4 t3 = *(const float4*)(tab + (size_t)b3*HH + c);
        acc.x += __uint_as_float(u0<<16)          * (t0.x + t0.y*f0);
        acc.y += __uint_as_float(u0 & 0xFFFF0000u)* (t0.z + t0.w*f0);
        acc.x += __uint_as_float(u1<<16)          * (t1.x + t1.y*f1);
        acc.y += __uint_as_float(u1 & 0xFFFF0000u)* (t1.z + t1.w*f1);
        acc.x += __uint_as_float(u2<<16)          * (t2.x + t2.y*f2);
        acc.y += __uint_as_float(u2 & 0xFFFF0000u)* (t2.z + t2.w*f2);
        acc.x += __uint_as_float(u3<<16)          * (t3.x + t3.y*f3);
        acc.y += __uint_as_float(u3 & 0xFFFF0000u)* (t3.z + t3.w*f3);
    }
    for (; p+2<=hi; p+=2){
        float2 r0 = rec[p], r1 = rec[p+1];
        GEDGE(r0, s0, b0, f0)
        GEDGE(r1, s1, b1, f1)
        unsigned u0 = *(const unsigned*)(hb + (size_t)s0*HH + c);
        unsigned u1 = *(const unsigned*)(hb + (size_t)s1*HH + c);
        float4 t0 = *(const float4*)(tab + (size_t)b0*HH + c);
        float4 t1 = *(const float4*)(tab + (size_t)b1*HH + c);
        acc.x += __uint_as_float(u0<<16)          * (t0.x + t0.y*f0);
        acc.y += __uint_as_float(u0 & 0xFFFF0000u)* (t0.z + t0.w*f0);
        acc.x += __uint_as_float(u1<<16)          * (t1.x + t1.y*f1);
        acc.y += __uint_as_float(u1 & 0xFFFF0000u)* (t1.z + t1.w*f1);
    }
    if (p < hi){
        float2 r0 = rec[p];
        GEDGE(r0, s0, b0, f0)
        unsigned u0 = *(const unsigned*)(hb + (size_t)s0*HH + c);
        float4 t0 = *(const float4*)(tab + (size_t)b0*HH + c);
        acc.x += __uint_as_float(u0<<16)          * (t0.x + t0.y*f0);
        acc.y += __uint_as_float(u0 & 0xFFFF0000u)* (t0.z + t0.w*f0);
    }
    unsigned pk = bf16rne(acc.x) | (bf16rne(acc.y)<<16);
    *(unsigned*)(aggp + (size_t)node*HH + c) = pk;
}

// ---------------- dual-branch node GEMM via MFMA bf16, no LDS, no barriers ----------------
__global__ __launch_bounds__(256) void k_gemm2m(
        const unsigned short* __restrict__ A1, const unsigned short* __restrict__ A2,
        const unsigned short* __restrict__ Bp0, const unsigned short* __restrict__ Bp1,
        const float* __restrict__ b1, const float* __restrict__ b2,
        const float* __restrict__ g1, const float* __restrict__ g2,
        const float* __restrict__ e1, const float* __restrict__ e2,
        float* __restrict__ C, unsigned short* __restrict__ Cb, int n){
    int tx = threadIdx.x;
    int l = tx & 63, wv = tx >> 6;
    int rb = blockIdx.x*LBM + wv*16;
    int mlo = l & 15, khi = l >> 4;
    int arow = rb + mlo;
    bool ok = arow < n;

    f32x4 acc0[8], acc1[8];
    #pragma unroll
    for (int ct=0;ct<8;ct++){ acc0[ct] = (f32x4)0.f; acc1[ct] = (f32x4)0.f; }

    {
        short8 af[4];
        const short8* ap = (const short8*)(A1 + (size_t)arow*HH);
        #pragma unroll
        for (int s=0;s<4;s++) af[s] = ok ? ap[s*4 + khi] : (short8)0;
        const short8* bp = (const short8*)Bp0;
        #pragma unroll
        for (int s=0;s<4;s++){
            #pragma unroll
            for (int ct=0;ct<8;ct++){
                short8 bf = bp[s*512 + ct*64 + l];
                acc0[ct] = __builtin_amdgcn_mfma_f32_16x16x32_bf16(af[s], bf, acc0[ct], 0, 0, 0);
            }
        }
    }
    {
        short8 af[4];
        const short8* ap = (const short8*)(A2 + (size_t)arow*HH);
        #pragma unroll
        for (int s=0;s<4;s++) af[s] = ok ? ap[s*4 + khi] : (short8)0;
        const short8* bp = (const short8*)Bp1;
        #pragma unroll
        for (int s=0;s<4;s++){
            #pragma unroll
            for (int ct=0;ct<8;ct++){
                short8 bf = bp[s*512 + ct*64 + l];
                acc1[ct] = __builtin_amdgcn_mfma_f32_16x16x32_bf16(af[s], bf, acc1[ct], 0, 0, 0);
            }
        }
    }

    #pragma unroll
    for (int ct=0;ct<8;ct++){
        int ncol = ct*16 + mlo;
        float bi1 = b1[ncol], ga1 = g1[ncol], bt1 = e1[ncol];
        float bi2 = b2[ncol], ga2 = g2[ncol], bt2 = e2[ncol];
        #pragma unroll
        for (int r=0;r<4;r++){
            int grow = rb + khi*4 + r;
            if (grow < n){
                float xv = acc0[ct][r] + bi1;
                xv = (xv>=0.f)? xv : 0.01f*xv;
                float yv = acc1[ct][r] + bi2;
                yv = (yv>=0.f)? yv : 0.01f*yv;
                float o = (ga1*xv + ga2*yv)*BN_INV + bt1 + bt2;
                if (C) C[(size_t)grow*HH + ncol] = o;
                Cb[(size_t)grow*HH + ncol] = (unsigned short)bf16rne(o);
            }
        }
    }
}

// ---------------- fused pool + FC x3 + head ----------------
static __device__ __forceinline__ int lower_bound_i(const int* __restrict__ a, int n, int key){
    int lo=0, hi=n;
    while (lo<hi){ int m=(lo+hi)>>1; if (a[m]<key) lo=m+1; else hi=m; }
    return lo;
}
__global__ void k_poolfc(const float* __restrict__ h,
                     const int* __restrict__ batch,
                     const float* __restrict__ fcW, const float* __restrict__ fcB,
                     const float* __restrict__ fbg, const float* __restrict__ fbb,
                     const float* __restrict__ outW, const float* __restrict__ outB,
                     float* __restrict__ out, int n){
    __shared__ float row[HH];
    __shared__ float red[2];
    int g = blockIdx.x, c = threadIdx.x;
    int lo = lower_bound_i(batch, n, g);
    int hi = lower_bound_i(batch, n, g+1);
    float v = 0.f;
    for (int r=lo; r<hi; r++) v += h[(size_t)r*HH + c];
    for (int l=0;l<3;l++){
        row[c] = v; __syncthreads();
        float acc = fcB[l*HH + c];
        const float* W = fcW + (size_t)l*HH*HH;
        #pragma unroll 8
        for (int k=0;k<HH;k++) acc += row[k]*W[k*HH + c];
        acc = (acc>=0.f)? acc : 0.01f*acc;
        v = fbg[l*HH+c]*acc*BN_INV + fbb[l*HH+c];
        __syncthreads();
    }
    float t = v * outW[c];
    #pragma unroll
    for (int o=32;o>0;o>>=1) t += __shfl_down(t, o, 64);
    if ((c&63)==0) red[c>>6] = t;
    __syncthreads();
    if (c==0) out[g] = red[0] + red[1] + outB[0];
}

extern "C" void kernel_launch(void* const* d_in, const int* in_sizes, int n_in,
                              void* d_out, int out_size, void* d_ws, size_t ws_size,
                              hipStream_t stream){
    const float* x      = (const float*)d_in[0];
    const float* pos    = (const float*)d_in[1];
    const float* W_in   = (const float*)d_in[2];
    const float* b_in   = (const float*)d_in[3];
    const float* coordW = (const float*)d_in[4];
    const float* coordB = (const float*)d_in[5];
    const float* nodeW  = (const float*)d_in[6];
    const float* nodeB  = (const float*)d_in[7];
    const float* bnG    = (const float*)d_in[8];
    const float* bnB    = (const float*)d_in[9];
    const float* fcW    = (const float*)d_in[10];
    const float* fcB    = (const float*)d_in[11];
    const float* fcBnG  = (const float*)d_in[12];
    const float* fcBnB  = (const float*)d_in[13];
    const float* outW   = (const float*)d_in[14];
    const float* outB   = (const float*)d_in[15];
    const int* ei1      = (const int*)d_in[16];
    const int* ei2      = (const int*)d_in[17];
    const int* batch    = (const int*)d_in[18];
    const int E1 = in_sizes[16]/2, E2 = in_sizes[17]/2;
    const int n = NN;
    const int n2 = 2*n;
    const int ET = E1 + E2;

    char* w = (char*)d_ws;
    size_t o = 0;
    auto alloc = [&](size_t bytes)->void*{
        void* r = w + o;
        o += (bytes + 255) & ~(size_t)255;
        return r;
    };
    unsigned short* hb    = (unsigned short*)alloc((size_t)n*HH*2);
    unsigned short* hb2   = (unsigned short*)alloc((size_t)n*HH*2);
    unsigned short* aggb1 = (unsigned short*)alloc((size_t)n*HH*2);
    unsigned short* aggb2 = (unsigned short*)alloc((size_t)n*HH*2);
    unsigned short* Bpk   = (unsigned short*)alloc((size_t)6*16384*2);
    float2* tabs = (float2*)alloc((size_t)6*NBINS*HH*8);
    float*  Wtg  = (float*)alloc((size_t)128*36*4);
    int*    off  = (int*)alloc((size_t)(n2+1)*4);
    int*    cnt  = (int*)alloc((size_t)n2*4);   // cnt and cur adjacent -> one memset
    int*    cur  = (int*)alloc((size_t)n2*4);
    float2* rec  = (float2*)alloc((size_t)ET*8);
    int*    bsum = (int*)alloc(1024*4);
    float*  hfin = (float*)alloc((size_t)n*HH*4);
    (void)n_in; (void)out_size; (void)ws_size;

    int nb2 = (n2+255)/256;

    hipMemsetAsync(cnt, 0, (size_t)2*n2*4, stream);
    k_count<<<(ET+255)/256,256,0,stream>>>(ei1, ei2, E1, E2, n, cnt);
    k_scan1<<<nb2,256,0,stream>>>(cnt, n2, off, bsum);
    k_scan2<<<1,1024,0,stream>>>(bsum, nb2);
    k_scan3<<<nb2,256,0,stream>>>(off, bsum, n2, ET);
    k_fill<<<(ET+255)/256,256,0,stream>>>(ei1, ei2, E1, E2, n, pos, off, cur, rec);
    k_prep<<<66+6144,256,0,stream>>>(nodeW, coordW, coordB, W_in, Bpk, tabs, Wtg);

    k_input<<<2048,256,0,stream>>>(x, Wtg, b_in, hb);

    int nb4 = (n+3)/4;
    unsigned short* hbcur = hb;
    unsigned short* hboth = hb2;
    for (int l=0; l<3; l++){
        int li0 = l*2, li1 = l*2+1;
        float* Cout = (l==2) ? hfin : nullptr;       // fp32 out only on final layer (poolfc)
        k_gather<<<2*nb4,256,0,stream>>>(hbcur, off, rec,
            tabs + (size_t)li0*NBINS*HH, tabs + (size_t)li1*NBINS*HH,
            aggb1, aggb2, n, nb4);
        k_gemm2m<<<(n+LBM-1)/LBM,256,0,stream>>>(aggb1, aggb2,
            Bpk + (size_t)li0*16384, Bpk + (size_t)li1*16384,
            nodeB + (size_t)li0*HH,  nodeB + (size_t)li1*HH,
            bnG   + (size_t)li0*HH,  bnG   + (size_t)li1*HH,
            bnB   + (size_t)li0*HH,  bnB   + (size_t)li1*HH,
            Cout, hboth, n);
        unsigned short* tb = hbcur; hbcur = hboth; hboth = tb;
    }

    k_poolfc<<<GG,128,0,stream>>>(hfin, batch, fcW, fcB, fcBnG, fcBnB, outW, outB, (float*)d_out, n);
}

// Round 14
// 531.525 us; speedup vs baseline: 1.5550x; 1.0361x over previous
//
#include <hip/hip_runtime.h>
#include <hip/hip_fp16.h>
#include <math.h>

#define NN   100000
#define HH   128
#define INF_ 35
#define GG   1000
#define LBM  64
#define NBINS 2048
#define DSCALE 128.0f      /* NBINS / 16.0 */
#define DINV   0.0078125f  /* 16.0 / NBINS */
#define DCLAMP 15.992f     /* ensures bin <= 2046 */

typedef __attribute__((ext_vector_type(8))) short short8;
typedef __attribute__((ext_vector_type(4))) float f32x4;

static __device__ __forceinline__ float silu_f(float x){ return x / (1.f + __expf(-x)); }
static __device__ __forceinline__ unsigned bf16rne(float x){
    unsigned u = __float_as_uint(x);
    return (u + 0x7FFFu + ((u>>16)&1u)) >> 16;
}
#define BN_INV 0.9999950000374997f  /* 1/sqrt(1+1e-5) */

// ---------------- stacked CSR build (both graphs, dst' = dst + n*branch) ----------------
__global__ void k_count(const int* __restrict__ ei1, const int* __restrict__ ei2,
                        int E1, int E2, int n, int* __restrict__ deg){
    int e = blockIdx.x*256 + threadIdx.x;
    int ET = E1 + E2;
    if (e >= ET) return;
    int c;
    if (e < E1) c = ei1[E1 + e];
    else        c = n + ei2[E2 + (e - E1)];
    atomicAdd(&deg[c], 1);
}

__global__ void k_scan1(const int* __restrict__ deg, int n2, int* __restrict__ off, int* __restrict__ bsum){
    __shared__ int s[256];
    int tid = threadIdx.x; int i = blockIdx.x*256 + tid;
    int v = (i<n2)? deg[i] : 0;
    s[tid] = v; __syncthreads();
    for (int ofs=1; ofs<256; ofs<<=1){
        int t = (tid>=ofs)? s[tid-ofs] : 0;
        __syncthreads(); s[tid] += t; __syncthreads();
    }
    if (i<n2) off[i] = s[tid] - v;
    if (tid==255) bsum[blockIdx.x] = s[255];
}

__global__ void k_scan2(int* __restrict__ bsum, int nb){
    __shared__ int s[1024];
    int tid = threadIdx.x;
    int v = (tid<nb)? bsum[tid] : 0;
    s[tid] = v; __syncthreads();
    for (int ofs=1; ofs<1024; ofs<<=1){
        int t = (tid>=ofs)? s[tid-ofs] : 0;
        __syncthreads(); s[tid] += t; __syncthreads();
    }
    if (tid<nb) bsum[tid] = s[tid] - v;
}

__global__ void k_scan3(int* __restrict__ off, const int* __restrict__ bsum, int n2, int ET){
    int i = blockIdx.x*256 + threadIdx.x;
    if (i<n2) off[i] += bsum[i>>8];
    if (i==0) off[n2] = ET;
}

// fill stacked CSR records: {src, d} = 8B
__global__ void k_fill(const int* __restrict__ ei1, const int* __restrict__ ei2,
                       int E1, int E2, int n, const float* __restrict__ pos,
                       const int* __restrict__ off, int* __restrict__ cur,
                       float2* __restrict__ rec){
    int e = blockIdx.x*256 + threadIdx.x;
    int ET = E1 + E2;
    if (e >= ET) return;
    int r, creal, cslot;
    if (e < E1){ r = ei1[e];        creal = ei1[E1 + e];        cslot = creal; }
    else       { int ee = e - E1; r = ei2[ee]; creal = ei2[E2 + ee]; cslot = n + creal; }
    int slot = atomicAdd(&cur[cslot], 1);
    int p = off[cslot] + slot;
    float dx = pos[r*3+0]-pos[creal*3+0];
    float dy = pos[r*3+1]-pos[creal*3+1];
    float dz = pos[r*3+2]-pos[creal*3+2];
    float d  = sqrtf(dx*dx + dy*dy + dz*dz);
    rec[p] = make_float2(__int_as_float(r), d);
}

// ---------------- fused prep: nodeW MFMA-pack + fp16 (value,slope) radial tables + transposed W_in ----------------
// blocks [0,48): pack ; [48,66): Wtg ; [66, 66+6144): table
__global__ void k_prep(const float* __restrict__ nodeW,
                       const float* __restrict__ coordW, const float* __restrict__ coordB,
                       const float* __restrict__ W_in,
                       unsigned short* __restrict__ Bpk, unsigned short* __restrict__ tabs,
                       float* __restrict__ Wtg){
    int blk = blockIdx.x, tx = threadIdx.x;
    if (blk < 48){
        int idx = blk*256 + tx;                  // < 12288
        if (idx >= 6*2048) return;
        int li = idx >> 11;
        int r  = idx & 2047;
        int s  = r >> 9;
        int r2 = r & 511;
        int ct = r2 >> 6;
        int l  = r2 & 63;
        const float* src = nodeW + (size_t)li*16384 + (size_t)(s*32 + (l>>4)*8)*HH + ct*16 + (l&15);
        unsigned short o[8];
        #pragma unroll
        for (int j=0;j<8;j++) o[j] = (unsigned short)bf16rne(src[(size_t)j*HH]);
        uint4 v;
        v.x = o[0] | ((unsigned)o[1]<<16);
        v.y = o[2] | ((unsigned)o[3]<<16);
        v.z = o[4] | ((unsigned)o[5]<<16);
        v.w = o[6] | ((unsigned)o[7]<<16);
        *(uint4*)(Bpk + (size_t)idx*8) = v;
    } else if (blk < 66){
        int i = (blk-48)*256 + tx;               // < 4608
        if (i >= 128*36) return;
        int c = i/36, k = i - c*36;
        Wtg[i] = (k < INF_) ? W_in[k*HH + c] : 0.f;
    } else {
        int idx = (blk-66)*256 + tx;             // < 1572864
        if (idx >= 6*NBINS*HH) return;
        int li  = idx / (NBINS*HH);
        int rem = idx - li*(NBINS*HH);
        int bin = rem >> 7;
        int col = rem & 127;
        float d0 = (float)bin * DINV;
        float d1 = d0 + DINV;
        const float* cW = coordW + (size_t)li*9*HH;
        float cb = coordB[li*HH + col];
        float q0 = cb, q1 = cb;
        #pragma unroll
        for (int k=0;k<9;k++){
            float wk = cW[k*HH + col];
            float t0 = 1.5f*d0 - 1.125f*(float)k;
            float t1 = 1.5f*d1 - 1.125f*(float)k;
            q0 += __expf(-t0*t0) * wk;
            q1 += __expf(-t1*t1) * wk;
        }
        float v = silu_f(q0);
        float s = silu_f(q1) - v;
        __half hv = __float2half_rn(v);
        __half hs = __float2half_rn(s);
        tabs[(size_t)idx*2+0] = __half_as_ushort(hv);
        tabs[(size_t)idx*2+1] = __half_as_ushort(hs);
    }
}

// ---------------- input: hb = bf16(silu(x @ W_in + b)); W streamed from L2 ----------------
#define NT_IN (NN/16)
__global__ __launch_bounds__(256) void k_input(const float* __restrict__ x,
        const float* __restrict__ Wtg, const float* __restrict__ b,
        unsigned short* __restrict__ hb){
    __shared__ __align__(16) float xs[16][36];
    int tx = threadIdx.x;
    int c = tx & 127, g = tx >> 7;
    float bc = b[c];
    const float4* wp = (const float4*)(Wtg + c*36);
    for (int tile = blockIdx.x; tile < NT_IN; tile += gridDim.x){
        int r0 = tile*16;
        for (int i = tx; i < 16*INF_; i += 256){
            int rr = i/INF_, kk = i - rr*INF_;
            xs[rr][kk] = x[(size_t)(r0+rr)*INF_ + kk];
        }
        if (tx < 16) xs[tx][35] = 0.f;
        __syncthreads();
        float acc[8];
        #pragma unroll
        for (int j=0;j<8;j++) acc[j] = bc;
        #pragma unroll
        for (int kk=0;kk<9;kk++){
            float4 w4 = wp[kk];
            #pragma unroll
            for (int j=0;j<8;j++){
                float4 xv = *(const float4*)(&xs[g*8+j][kk*4]);
                acc[j] += xv.x*w4.x + xv.y*w4.y + xv.z*w4.z + xv.w*w4.w;
            }
        }
        #pragma unroll
        for (int j=0;j<8;j++){
            int gr = r0 + g*8 + j;
            hb[(size_t)gr*HH + c] = (unsigned short)bf16rne(silu_f(acc[j]));
        }
        __syncthreads();
    }
}

// ---------------- merged dual-branch gather: fp16 (v,slope) table, bf16 h, 4-edge unroll ----------------
#define GEDGE(RP, S_, B_, F_)                                        \
    int S_ = __float_as_int((RP).x);                                 \
    float db_##S_ = fminf((RP).y, DCLAMP)*DSCALE;                    \
    int B_ = (int)db_##S_; float F_ = db_##S_ - (float)B_;

// unpack uint2 of {v0,s0,v1,s1} fp16 and accumulate
#define GACC(U_, T_, F_)                                             \
    {                                                                \
        float2 p0 = __half22float2(*(const __half2*)&(T_).x);        \
        float2 p1 = __half22float2(*(const __half2*)&(T_).y);        \
        acc.x += __uint_as_float((U_)<<16)           * (p0.x + p0.y*(F_)); \
        acc.y += __uint_as_float((U_) & 0xFFFF0000u) * (p1.x + p1.y*(F_)); \
    }

__global__ __launch_bounds__(256) void k_gather(
        const unsigned short* __restrict__ hb,
        const int* __restrict__ off, const float2* __restrict__ rec,
        const unsigned short* __restrict__ tab0, const unsigned short* __restrict__ tab1,
        unsigned short* __restrict__ aggb1, unsigned short* __restrict__ aggb2,
        int n, int nblk1){
    int b = blockIdx.x;
    int br = (b >= nblk1) ? 1 : 0;
    int node = (br ? b - nblk1 : b)*4 + (threadIdx.x>>6);
    if (node >= n) return;
    int c = (threadIdx.x & 63)*2;
    const unsigned short* tab = br ? tab1 : tab0;
    unsigned short* aggp = br ? aggb2 : aggb1;

    float2 acc;
    {
        unsigned u = *(const unsigned*)(hb + (size_t)node*HH + c);
        acc.x = __uint_as_float(u<<16); acc.y = __uint_as_float(u & 0xFFFF0000u);
    }

    int slot = node + br*n;
    int lo = off[slot], hi = off[slot+1];
    lo = __builtin_amdgcn_readfirstlane(lo);
    hi = __builtin_amdgcn_readfirstlane(hi);

    int p = lo;
    for (; p+4<=hi; p+=4){
        float2 r0 = rec[p], r1 = rec[p+1], r2 = rec[p+2], r3 = rec[p+3];
        GEDGE(r0, s0, b0, f0)
        GEDGE(r1, s1, b1, f1)
        GEDGE(r2, s2, b2, f2)
        GEDGE(r3, s3, b3, f3)
        unsigned u0 = *(const unsigned*)(hb + (size_t)s0*HH + c);
        unsigned u1 = *(const unsigned*)(hb + (size_t)s1*HH + c);
        unsigned u2 = *(const unsigned*)(hb + (size_t)s2*HH + c);
        unsigned u3 = *(const unsigned*)(hb + (size_t)s3*HH + c);
        uint2 t0 = *(const uint2*)(tab + ((size_t)b0*HH + c)*2);
        uint2 t1 = *(const uint2*)(tab + ((size_t)b1*HH + c)*2);
        uint2 t2 = *(const uint2*)(tab + ((size_t)b2*HH + c)*2);
        uint2 t3 = *(const uint2*)(tab + ((size_t)b3*HH + c)*2);
        GACC(u0, t0, f0)
        GACC(u1, t1, f1)
        GACC(u2, t2, f2)
        GACC(u3, t3, f3)
    }
    for (; p+2<=hi; p+=2){
        float2 r0 = rec[p], r1 = rec[p+1];
        GEDGE(r0, s0, b0, f0)
        GEDGE(r1, s1, b1, f1)
        unsigned u0 = *(const unsigned*)(hb + (size_t)s0*HH + c);
        unsigned u1 = *(const unsigned*)(hb + (size_t)s1*HH + c);
        uint2 t0 = *(const uint2*)(tab + ((size_t)b0*HH + c)*2);
        uint2 t1 = *(const uint2*)(tab + ((size_t)b1*HH + c)*2);
        GACC(u0, t0, f0)
        GACC(u1, t1, f1)
    }
    if (p < hi){
        float2 r0 = rec[p];
        GEDGE(r0, s0, b0, f0)
        unsigned u0 = *(const unsigned*)(hb + (size_t)s0*HH + c);
        uint2 t0 = *(const uint2*)(tab + ((size_t)b0*HH + c)*2);
        GACC(u0, t0, f0)
    }
    unsigned pk = bf16rne(acc.x) | (bf16rne(acc.y)<<16);
    *(unsigned*)(aggp + (size_t)node*HH + c) = pk;
}

// ---------------- dual-branch node GEMM via MFMA bf16, no LDS, no barriers ----------------
__global__ __launch_bounds__(256) void k_gemm2m(
        const unsigned short* __restrict__ A1, const unsigned short* __restrict__ A2,
        const unsigned short* __restrict__ Bp0, const unsigned short* __restrict__ Bp1,
        const float* __restrict__ b1, const float* __restrict__ b2,
        const float* __restrict__ g1, const float* __restrict__ g2,
        const float* __restrict__ e1, const float* __restrict__ e2,
        float* __restrict__ C, unsigned short* __restrict__ Cb, int n){
    int tx = threadIdx.x;
    int l = tx & 63, wv = tx >> 6;
    int rb = blockIdx.x*LBM + wv*16;
    int mlo = l & 15, khi = l >> 4;
    int arow = rb + mlo;
    bool ok = arow < n;

    f32x4 acc0[8], acc1[8];
    #pragma unroll
    for (int ct=0;ct<8;ct++){ acc0[ct] = (f32x4)0.f; acc1[ct] = (f32x4)0.f; }

    {
        short8 af[4];
        const short8* ap = (const short8*)(A1 + (size_t)arow*HH);
        #pragma unroll
        for (int s=0;s<4;s++) af[s] = ok ? ap[s*4 + khi] : (short8)0;
        const short8* bp = (const short8*)Bp0;
        #pragma unroll
        for (int s=0;s<4;s++){
            #pragma unroll
            for (int ct=0;ct<8;ct++){
                short8 bf = bp[s*512 + ct*64 + l];
                acc0[ct] = __builtin_amdgcn_mfma_f32_16x16x32_bf16(af[s], bf, acc0[ct], 0, 0, 0);
            }
        }
    }
    {
        short8 af[4];
        const short8* ap = (const short8*)(A2 + (size_t)arow*HH);
        #pragma unroll
        for (int s=0;s<4;s++) af[s] = ok ? ap[s*4 + khi] : (short8)0;
        const short8* bp = (const short8*)Bp1;
        #pragma unroll
        for (int s=0;s<4;s++){
            #pragma unroll
            for (int ct=0;ct<8;ct++){
                short8 bf = bp[s*512 + ct*64 + l];
                acc1[ct] = __builtin_amdgcn_mfma_f32_16x16x32_bf16(af[s], bf, acc1[ct], 0, 0, 0);
            }
        }
    }

    #pragma unroll
    for (int ct=0;ct<8;ct++){
        int ncol = ct*16 + mlo;
        float bi1 = b1[ncol], ga1 = g1[ncol], bt1 = e1[ncol];
        float bi2 = b2[ncol], ga2 = g2[ncol], bt2 = e2[ncol];
        #pragma unroll
        for (int r=0;r<4;r++){
            int grow = rb + khi*4 + r;
            if (grow < n){
                float xv = acc0[ct][r] + bi1;
                xv = (xv>=0.f)? xv : 0.01f*xv;
                float yv = acc1[ct][r] + bi2;
                yv = (yv>=0.f)? yv : 0.01f*yv;
                float o = (ga1*xv + ga2*yv)*BN_INV + bt1 + bt2;
                if (C) C[(size_t)grow*HH + ncol] = o;
                Cb[(size_t)grow*HH + ncol] = (unsigned short)bf16rne(o);
            }
        }
    }
}

// ---------------- fused pool + FC x3 + head ----------------
static __device__ __forceinline__ int lower_bound_i(const int* __restrict__ a, int n, int key){
    int lo=0, hi=n;
    while (lo<hi){ int m=(lo+hi)>>1; if (a[m]<key) lo=m+1; else hi=m; }
    return lo;
}
__global__ void k_poolfc(const float* __restrict__ h,
                     const int* __restrict__ batch,
                     const float* __restrict__ fcW, const float* __restrict__ fcB,
                     const float* __restrict__ fbg, const float* __restrict__ fbb,
                     const float* __restrict__ outW, const float* __restrict__ outB,
                     float* __restrict__ out, int n){
    __shared__ float row[HH];
    __shared__ float red[2];
    int g = blockIdx.x, c = threadIdx.x;
    int lo = lower_bound_i(batch, n, g);
    int hi = lower_bound_i(batch, n, g+1);
    float v = 0.f;
    for (int r=lo; r<hi; r++) v += h[(size_t)r*HH + c];
    for (int l=0;l<3;l++){
        row[c] = v; __syncthreads();
        float acc = fcB[l*HH + c];
        const float* W = fcW + (size_t)l*HH*HH;
        #pragma unroll 8
        for (int k=0;k<HH;k++) acc += row[k]*W[k*HH + c];
        acc = (acc>=0.f)? acc : 0.01f*acc;
        v = fbg[l*HH+c]*acc*BN_INV + fbb[l*HH+c];
        __syncthreads();
    }
    float t = v * outW[c];
    #pragma unroll
    for (int o=32;o>0;o>>=1) t += __shfl_down(t, o, 64);
    if ((c&63)==0) red[c>>6] = t;
    __syncthreads();
    if (c==0) out[g] = red[0] + red[1] + outB[0];
}

extern "C" void kernel_launch(void* const* d_in, const int* in_sizes, int n_in,
                              void* d_out, int out_size, void* d_ws, size_t ws_size,
                              hipStream_t stream){
    const float* x      = (const float*)d_in[0];
    const float* pos    = (const float*)d_in[1];
    const float* W_in   = (const float*)d_in[2];
    const float* b_in   = (const float*)d_in[3];
    const float* coordW = (const float*)d_in[4];
    const float* coordB = (const float*)d_in[5];
    const float* nodeW  = (const float*)d_in[6];
    const float* nodeB  = (const float*)d_in[7];
    const float* bnG    = (const float*)d_in[8];
    const float* bnB    = (const float*)d_in[9];
    const float* fcW    = (const float*)d_in[10];
    const float* fcB    = (const float*)d_in[11];
    const float* fcBnG  = (const float*)d_in[12];
    const float* fcBnB  = (const float*)d_in[13];
    const float* outW   = (const float*)d_in[14];
    const float* outB   = (const float*)d_in[15];
    const int* ei1      = (const int*)d_in[16];
    const int* ei2      = (const int*)d_in[17];
    const int* batch    = (const int*)d_in[18];
    const int E1 = in_sizes[16]/2, E2 = in_sizes[17]/2;
    const int n = NN;
    const int n2 = 2*n;
    const int ET = E1 + E2;

    char* w = (char*)d_ws;
    size_t o = 0;
    auto alloc = [&](size_t bytes)->void*{
        void* r = w + o;
        o += (bytes + 255) & ~(size_t)255;
        return r;
    };
    unsigned short* hb    = (unsigned short*)alloc((size_t)n*HH*2);
    unsigned short* hb2   = (unsigned short*)alloc((size_t)n*HH*2);
    unsigned short* aggb1 = (unsigned short*)alloc((size_t)n*HH*2);
    unsigned short* aggb2 = (unsigned short*)alloc((size_t)n*HH*2);
    unsigned short* Bpk   = (unsigned short*)alloc((size_t)6*16384*2);
    unsigned short* tabs  = (unsigned short*)alloc((size_t)6*NBINS*HH*4);  // fp16 (v,slope)
    float*  Wtg  = (float*)alloc((size_t)128*36*4);
    int*    off  = (int*)alloc((size_t)(n2+1)*4);
    int*    cnt  = (int*)alloc((size_t)n2*4);   // cnt and cur adjacent -> one memset
    int*    cur  = (int*)alloc((size_t)n2*4);
    float2* rec  = (float2*)alloc((size_t)ET*8);
    int*    bsum = (int*)alloc(1024*4);
    float*  hfin = (float*)alloc((size_t)n*HH*4);
    (void)n_in; (void)out_size; (void)ws_size;

    int nb2 = (n2+255)/256;

    hipMemsetAsync(cnt, 0, (size_t)2*n2*4, stream);
    k_count<<<(ET+255)/256,256,0,stream>>>(ei1, ei2, E1, E2, n, cnt);
    k_scan1<<<nb2,256,0,stream>>>(cnt, n2, off, bsum);
    k_scan2<<<1,1024,0,stream>>>(bsum, nb2);
    k_scan3<<<nb2,256,0,stream>>>(off, bsum, n2, ET);
    k_fill<<<(ET+255)/256,256,0,stream>>>(ei1, ei2, E1, E2, n, pos, off, cur, rec);
    k_prep<<<66+6144,256,0,stream>>>(nodeW, coordW, coordB, W_in, Bpk, tabs, Wtg);

    k_input<<<2048,256,0,stream>>>(x, Wtg, b_in, hb);

    int nb4 = (n+3)/4;
    unsigned short* hbcur = hb;
    unsigned short* hboth = hb2;
    for (int l=0; l<3; l++){
        int li0 = l*2, li1 = l*2+1;
        float* Cout = (l==2) ? hfin : nullptr;       // fp32 out only on final layer (poolfc)
        k_gather<<<2*nb4,256,0,stream>>>(hbcur, off, rec,
            tabs + (size_t)li0*NBINS*HH*2, tabs + (size_t)li1*NBINS*HH*2,
            aggb1, aggb2, n, nb4);
        k_gemm2m<<<(n+LBM-1)/LBM,256,0,stream>>>(aggb1, aggb2,
            Bpk + (size_t)li0*16384, Bpk + (size_t)li1*16384,
            nodeB + (size_t)li0*HH,  nodeB + (size_t)li1*HH,
            bnG   + (size_t)li0*HH,  bnG   + (size_t)li1*HH,
            bnB   + (size_t)li0*HH,  bnB   + (size_t)li1*HH,
            Cout, hboth, n);
        unsigned short* tb = hbcur; hbcur = hboth; hboth = tb;
    }

    k_poolfc<<<GG,128,0,stream>>>(hfin, batch, fcW, fcB, fcBnG, fcBnB, outW, outB, (float*)d_out, n);
}